// Round 3
// baseline (993.048 us; speedup 1.0000x reference)
//
#include <hip/hip_runtime.h>
#include <hip/hip_bf16.h>

#define NN 30000
#define NE 480000
#define NH 4
#define DH 64
#define MF 30
#define KG 10
#define RATIO 0.18257418583505536f   /* 1/sqrt(30) */
#define DNRM  0.35355339059327373f   /* 64^-0.25  */

// fp32 params block layout (element offsets)
#define P_WF    0        /* [768][256] Wq|Wk|Wv rows */
#define P_BF    196608   /* [768] bq|bk|bv */
#define P_WOF   197376   /* [64][256] Wo */
#define P_WOBF  213760   /* [64] Wo bias */
#define P_BBF   213824   /* [4] rb bias b */
#define P_PROJ  213828   /* [30][64] proj */
#define P_TAU   215748   /* scalar */
#define P_TOTAL 215749

typedef unsigned short u16;
typedef unsigned int   u32;
typedef __attribute__((ext_vector_type(8))) short bf16x8;
typedef __attribute__((ext_vector_type(4))) float f32x4;

__device__ __forceinline__ float u2f(u16 u) { return __uint_as_float(((u32)u) << 16); }
__device__ __forceinline__ u16  f2bf(float f) {  // round-to-nearest-even bf16
    u32 x = __float_as_uint(f);
    return (u16)((x + 0x7FFFu + ((x >> 16) & 1u)) >> 16);
}
// order-preserving float->uint encoding for atomicMax over signed floats
__device__ __forceinline__ u32  encf(float f) { u32 u = __float_as_uint(f); return (u & 0x80000000u) ? ~u : (u | 0x80000000u); }
__device__ __forceinline__ float decf(u32 u)  { return (u & 0x80000000u) ? __uint_as_float(u & 0x7FFFFFFFu) : __uint_as_float(~u); }

// ---------------- dtype detection (fp32 vs bf16 input tensors) ----------------
__global__ void k_detect(const u16* __restrict__ z, int* __restrict__ flag) {
    if (threadIdx.x == 0 && blockIdx.x == 0) {
        int bad = 0;
        for (int i = 0; i < 256; i += 2) {
            u16 u = z[i];
            int e = (u >> 7) & 0xFF;
            if (u != 0 && !(e >= 100 && e <= 140)) bad++;
        }
        *flag = (bad > 16) ? 1 : 0;   // 1 = inputs are fp32
    }
}

// ---------------- stage all small params to fp32 ----------------
__global__ __launch_bounds__(256) void k_cvt_params(
    const void* Wq, const void* Wk, const void* Wv,
    const void* bq, const void* bk, const void* bv,
    const void* Wo, const void* Wob, const void* bb, const void* proj,
    const void* taup, float* __restrict__ params, const int* __restrict__ flag)
{
    int i = blockIdx.x * 256 + threadIdx.x;
    if (i >= P_TOTAL) return;
    int f = *flag;
    if (i == P_TAU) {
        float v = f ? ((const float*)taup)[0] : u2f(((const u16*)taup)[0]);
        if (!(v > 1e-6f && v < 1e6f)) {
            float ff = ((const float*)taup)[0];
            v = (ff > 1e-6f && ff < 1e6f) ? ff : 0.25f;
        }
        params[i] = v;
        return;
    }
    const void* src; int j;
    if      (i < 65536)  { src = Wq;  j = i; }
    else if (i < 131072) { src = Wk;  j = i - 65536; }
    else if (i < 196608) { src = Wv;  j = i - 131072; }
    else if (i < 196864) { src = bq;  j = i - 196608; }
    else if (i < 197120) { src = bk;  j = i - 196864; }
    else if (i < 197376) { src = bv;  j = i - 197120; }
    else if (i < 213760) { src = Wo;  j = i - 197376; }
    else if (i < 213824) { src = Wob; j = i - 213760; }
    else if (i < 213828) { src = bb;  j = i - 213824; }
    else                 { src = proj; j = i - P_PROJ; }
    params[i] = f ? ((const float*)src)[j] : u2f(((const u16*)src)[j]);
}

// ---------------- hi/lo bf16 split of W (once; gemm staging becomes pure copy) ----------------
__global__ __launch_bounds__(256) void k_cvt_w(const float* __restrict__ params,
                                               u16* __restrict__ Wh, u16* __restrict__ Wl)
{
    int i = blockIdx.x * 256 + threadIdx.x;   // grid = 768 blocks, 196608 exact
    float x = params[P_WF + i];
    u16 h = f2bf(x);
    Wh[i] = h;
    Wl[i] = f2bf(x - u2f(h));
}

// ---------------- degrees ----------------
__global__ __launch_bounds__(256) void k_deg(const int* __restrict__ ei, int* __restrict__ din, int* __restrict__ dout) {
    int e = blockIdx.x * 256 + threadIdx.x;
    if (e >= NE) return;
    atomicAdd(&dout[ei[e]], 1);
    atomicAdd(&din[ei[NE + e]], 1);
}

// ---------------- scan-free CSR offsets ----------------
__global__ __launch_bounds__(256) void k_off(const int* __restrict__ din, int* __restrict__ offn, int* __restrict__ counter) {
    __shared__ int s[256];
    __shared__ int base;
    int tid = threadIdx.x;
    int n = blockIdx.x * 256 + tid;
    int v = (n < NN) ? din[n] : 0;
    s[tid] = v;
    __syncthreads();
    for (int o = 1; o < 256; o <<= 1) {
        int t = (tid >= o) ? s[tid - o] : 0;
        __syncthreads();
        s[tid] += t;
        __syncthreads();
    }
    if (tid == 255) base = atomicAdd(counter, s[255]);
    __syncthreads();
    if (n < NN) offn[n] = base + s[tid] - v;
}

// fill CSR + precompute per-edge conv weight w = rsqrt(din[t]*dout[s])
__global__ __launch_bounds__(256) void k_fill(const int* __restrict__ ei, const int* __restrict__ offn,
                                              int* __restrict__ fill, int* __restrict__ csr,
                                              const int* __restrict__ din, const int* __restrict__ dout,
                                              float* __restrict__ wedge) {
    int e = blockIdx.x * 256 + threadIdx.x;
    if (e >= NE) return;
    int s = ei[e], t = ei[NE + e];
    int pos = offn[t] + atomicAdd(&fill[t], 1);
    csr[pos] = s;
    wedge[pos] = rsqrtf((float)din[t] * (float)dout[s]);
}

// ---------------- fused QKV GEMM (bf16 MFMA, hi/lo split) + Performer epilogue ----------------
// grid (ceil(NN/64), 12): y 0..3 -> Q head y; y 4..7 -> K head y-4; y 8..11 -> V cols.
// fp32 inputs: A,B split into hi+lo bf16 planes; C = Ah*Bh + Ah*Bl + Al*Bh (3 MFMA passes,
// rel err ~2^-17 -- below the bf16 noise already accepted downstream). bf16 inputs: 1 exact pass.
// LDS planes are 128B-row tiles with T2 XOR swizzle (byte ^= (row&7)<<4) on write AND read.
__global__ __launch_bounds__(256) void k_gemm_feat(
    const void* __restrict__ zv, const float* __restrict__ params, const int* __restrict__ flag,
    const u16* __restrict__ Wh, const u16* __restrict__ Wl,
    u16* __restrict__ V16, float* __restrict__ qp, u16* __restrict__ qp16,
    float* __restrict__ dashK, float* __restrict__ diagK, u32* __restrict__ stab)
{
    __shared__ __align__(16) char smemc[32768];  // 4 bf16 planes of 64x64 (8 KB each)
    __shared__ u32 smaxL;
    char* AsH = smemc;                // A hi plane
    char* AsL = smemc + 8192;         // A lo plane
    char* BsH = smemc + 16384;        // B hi plane
    char* BsL = smemc + 24576;        // B lo plane
    float* tile  = (float*)smemc;          // 64 x 68 fp32 epilogue tile (overlays planes)
    float* projL = (float*)smemc + 4352;   // 30 x 65 (overlays planes; staged after GEMM)

    const int tid = threadIdx.x;
    const int bm = blockIdx.x * 64;
    const int bn = blockIdx.y * 64;
    const int f32 = *flag;
    const int wave = tid >> 6, lane = tid & 63;
    const int wm = wave >> 1, wn = wave & 1;     // 2x2 wave grid, each wave 32x32
    const int sr = tid >> 2;                     // staging row 0..63
    const int sc = (tid & 3) * 16;               // staging col base (16 cols/thread/chunk)

    f32x4 acc[2][2] = {};

    for (int k0 = 0; k0 < 256; k0 += 64) {
        __syncthreads();
        // ---------- stage A (z), hi/lo split on the fly ----------
        {
            int zrow = bm + sr;
            if (f32) {
                float x[16];
                if (zrow < NN) {
                    const float4* zp = (const float4*)((const float*)zv + (size_t)zrow * 256 + k0 + sc);
                    #pragma unroll
                    for (int q4 = 0; q4 < 4; ++q4) {
                        float4 v = zp[q4];
                        x[q4 * 4 + 0] = v.x; x[q4 * 4 + 1] = v.y;
                        x[q4 * 4 + 2] = v.z; x[q4 * 4 + 3] = v.w;
                    }
                } else {
                    #pragma unroll
                    for (int j = 0; j < 16; ++j) x[j] = 0.f;
                }
                #pragma unroll
                for (int j8 = 0; j8 < 2; ++j8) {
                    u32 hw[4], lw[4];
                    #pragma unroll
                    for (int p = 0; p < 4; ++p) {
                        float a = x[j8 * 8 + 2 * p], b2 = x[j8 * 8 + 2 * p + 1];
                        u16 ha = f2bf(a), hb = f2bf(b2);
                        hw[p] = (u32)ha | ((u32)hb << 16);
                        u16 la = f2bf(a - u2f(ha)), lb = f2bf(b2 - u2f(hb));
                        lw[p] = (u32)la | ((u32)lb << 16);
                    }
                    int byt = sr * 128 + (((sc + j8 * 8) * 2) ^ ((sr & 7) << 4));
                    *(uint4*)(AsH + byt) = make_uint4(hw[0], hw[1], hw[2], hw[3]);
                    *(uint4*)(AsL + byt) = make_uint4(lw[0], lw[1], lw[2], lw[3]);
                }
            } else {
                uint4 v0 = make_uint4(0, 0, 0, 0), v1 = v0;
                if (zrow < NN) {
                    const uint4* zp = (const uint4*)((const u16*)zv + (size_t)zrow * 256 + k0 + sc);
                    v0 = zp[0]; v1 = zp[1];
                }
                int byt0 = sr * 128 + (((sc + 0) * 2) ^ ((sr & 7) << 4));
                int byt1 = sr * 128 + (((sc + 8) * 2) ^ ((sr & 7) << 4));
                *(uint4*)(AsH + byt0) = v0;
                *(uint4*)(AsH + byt1) = v1;
            }
        }
        // ---------- stage B (preconverted W hi/lo: pure copy) ----------
        {
            int byt0 = sr * 128 + (((sc + 0) * 2) ^ ((sr & 7) << 4));
            int byt1 = sr * 128 + (((sc + 8) * 2) ^ ((sr & 7) << 4));
            const uint4* wh4 = (const uint4*)(Wh + (size_t)(bn + sr) * 256 + k0 + sc);
            *(uint4*)(BsH + byt0) = wh4[0];
            *(uint4*)(BsH + byt1) = wh4[1];
            if (f32) {
                const uint4* wl4 = (const uint4*)(Wl + (size_t)(bn + sr) * 256 + k0 + sc);
                *(uint4*)(BsL + byt0) = wl4[0];
                *(uint4*)(BsL + byt1) = wl4[1];
            }
        }
        __syncthreads();
        // ---------- MFMA: 2 k-steps of 32 per chunk ----------
        #pragma unroll
        for (int kk = 0; kk < 2; ++kk) {
            const int kb = (kk * 32 + ((lane >> 4) * 8)) * 2;   // byte col of this lane's 8 k-elems
            bf16x8 ah[2], bh[2], al[2], bl[2];
            #pragma unroll
            for (int i = 0; i < 2; ++i) {
                int ar = 32 * wm + 16 * i + (lane & 15);
                int ab = ar * 128 + (kb ^ ((ar & 7) << 4));
                ah[i] = *(const bf16x8*)(AsH + ab);
                int br = 32 * wn + 16 * i + (lane & 15);
                int bb2 = br * 128 + (kb ^ ((br & 7) << 4));
                bh[i] = *(const bf16x8*)(BsH + bb2);
                if (f32) {
                    al[i] = *(const bf16x8*)(AsL + ab);
                    bl[i] = *(const bf16x8*)(BsL + bb2);
                }
            }
            #pragma unroll
            for (int i = 0; i < 2; ++i)
                #pragma unroll
                for (int nf = 0; nf < 2; ++nf) {
                    acc[i][nf] = __builtin_amdgcn_mfma_f32_16x16x32_bf16(ah[i], bh[nf], acc[i][nf], 0, 0, 0);
                    if (f32) {
                        acc[i][nf] = __builtin_amdgcn_mfma_f32_16x16x32_bf16(ah[i], bl[nf], acc[i][nf], 0, 0, 0);
                        acc[i][nf] = __builtin_amdgcn_mfma_f32_16x16x32_bf16(al[i], bh[nf], acc[i][nf], 0, 0, 0);
                    }
                }
        }
    }
    __syncthreads();   // all plane reads done; smem reusable as tile/projL

    const float* bfv = params + P_BF;
    if (bn >= 512) {   // ---- V: acc -> tile (+bias) -> coalesced bf16 store ----
        #pragma unroll
        for (int i = 0; i < 2; ++i)
            #pragma unroll
            for (int nf = 0; nf < 2; ++nf) {
                int col = 32 * wn + 16 * nf + (lane & 15);
                float bias = bfv[bn + col];
                #pragma unroll
                for (int r2 = 0; r2 < 4; ++r2) {
                    int row = 32 * wm + 16 * i + ((lane >> 4) * 4) + r2;
                    tile[row * 68 + col] = acc[i][nf][r2] + bias;
                }
            }
        __syncthreads();
        for (int i2 = tid; i2 < 4096; i2 += 256) {
            int row = i2 >> 6, col = i2 & 63;
            int nrow = bm + row;
            if (nrow < NN) V16[(size_t)nrow * 256 + (bn - 512) + col] = f2bf(tile[row * 68 + col]);
        }
        return;
    }

    // ---- Q/K: performer features on the 64x64 head tile ----
    for (int i2 = tid; i2 < MF * DH; i2 += 256) projL[(i2 >> 6) * 65 + (i2 & 63)] = params[P_PROJ + i2];
    if (tid == 0) smaxL = 0u;
    float scale = DNRM * rsqrtf(params[P_TAU]);
    #pragma unroll
    for (int i = 0; i < 2; ++i)
        #pragma unroll
        for (int nf = 0; nf < 2; ++nf) {
            int col = 32 * wn + 16 * nf + (lane & 15);
            float bias = bfv[bn + col];
            #pragma unroll
            for (int r2 = 0; r2 < 4; ++r2) {
                int row = 32 * wm + 16 * i + ((lane >> 4) * 4) + r2;
                tile[row * 68 + col] = (acc[i][nf][r2] + bias) * scale;
            }
        }
    __syncthreads();

    int r = tid >> 2, q = tid & 3;      // 4 lanes cooperate per row; same wave
    int n = bm + r;
    const float* trow = tile + r * 68;
    float dp = 0.f;
    #pragma unroll
    for (int d = q * 16; d < q * 16 + 16; ++d) dp += trow[d] * trow[d];
    dp += __shfl_xor(dp, 1);
    dp += __shfl_xor(dp, 2);
    float diag = dp * 0.5f;

    float dm[8];
    int nm = 0;
    float lmax = -3.0e38f;
    for (int m = q; m < MF; m += 4) {
        float s = 0.f;
        #pragma unroll
        for (int d = 0; d < DH; ++d) s += trow[d] * projL[m * 65 + d];
        dm[nm++] = s;
        lmax = fmaxf(lmax, s);
    }
    float mx = fmaxf(lmax, __shfl_xor(lmax, 1));
    mx = fmaxf(mx, __shfl_xor(mx, 2));

    if (bn < 256) {   // Q: row-local stab, write qp (fp32) + packed bf16 copy
        int h = blockIdx.y;
        if (n < NN) {
            float* o = qp + ((size_t)n * NH + h) * MF;
            u16* o16 = qp16 + ((size_t)n * NH + h) * 32;
            nm = 0;
            for (int m = q; m < MF; m += 4) {
                float v = RATIO * (expf(dm[nm++] - diag - mx) + 1e-6f);
                o[m] = v;
                o16[m] = f2bf(v);
            }
            if (q == 0) { o16[30] = 0; o16[31] = 0; }
        }
    } else {          // K: store dash/diag, global per-head max
        int h = blockIdx.y - 4;
        if (n < NN) {
            float* o = dashK + ((size_t)n * NH + h) * MF;
            nm = 0;
            for (int m = q; m < MF; m += 4) o[m] = dm[nm++];
            if (q == 0) {
                diagK[(size_t)n * NH + h] = diag;
                atomicMax(&smaxL, encf(mx));
            }
        }
        __syncthreads();
        if (tid == 0) atomicMax(&stab[h], smaxL);
    }
}

// ---------------- keys pass 2: kp in-place + kpsum + packed bf16 copy ----------------
__global__ __launch_bounds__(256) void k_kp(float* __restrict__ kp, const float* __restrict__ diagK,
                                            const u32* __restrict__ stab, float* __restrict__ kpsum,
                                            u16* __restrict__ kp16)
{
    __shared__ float part[NH * MF];
    __shared__ float stabf[4];
    int tid = threadIdx.x;
    if (tid < NH * MF) part[tid] = 0.f;
    if (tid >= 128 && tid < 132) stabf[tid - 128] = decf(stab[tid - 128]);
    __syncthreads();
    int base = blockIdx.x * 64 * MF;   // 64 rows/block, exact: 1875*64 = 120000
    for (int i = tid; i < 64 * MF; i += 256) {
        int row = blockIdx.x * 64 + i / MF;
        int m = i - (i / MF) * MF;
        int h = row & 3;
        float v = RATIO * (expf(kp[base + i] - diagK[row] - stabf[h]) + 1e-6f);
        kp[base + i] = v;
        kp16[(size_t)row * 32 + m] = f2bf(v);
        atomicAdd(&part[h * MF + m], v);
    }
    if (tid < 64) {
        int row = blockIdx.x * 64 + tid;
        kp16[(size_t)row * 32 + 30] = 0;
        kp16[(size_t)row * 32 + 31] = 0;
    }
    __syncthreads();
    if (tid < NH * MF) atomicAdd(&kpsum[tid], part[tid]);
}

// ---------------- attn_norm[n,h] = qp[n,h,:] . kpsum[h,:] ----------------
__global__ __launch_bounds__(256) void k_an(const float* __restrict__ qp, const float* __restrict__ kpsum,
                                            float* __restrict__ an)
{
    __shared__ float kps[NH * MF];
    int tid = threadIdx.x;
    if (tid < NH * MF) kps[tid] = kpsum[tid];
    __syncthreads();
    int idx = blockIdx.x * 256 + tid;
    if (idx >= NN * NH) return;
    int h = idx & 3;
    const float* q = qp + (size_t)idx * MF;
    float s = 0.f;
    #pragma unroll
    for (int m = 0; m < MF; ++m) s += q[m] * kps[h * MF + m];
    an[idx] = s;
}

// ---------------- kvs partial reduction over nodes (two-stage, NO atomics) ----------------
#define KVS_CHUNKS 50
#define KVS_NPB (NN / KVS_CHUNKS)    /* 600 nodes per block */
#define KVS_TS 40                    /* nodes per LDS tile */
#define KVS_DZ 16                    /* d-slice width, grid.z = DH/KVS_DZ = 4 */
__global__ __launch_bounds__(320) void k_kvs(const float* __restrict__ kp, const void* __restrict__ gum,
                                             const u16* __restrict__ V16, const int* __restrict__ flag,
                                             float* __restrict__ Pkvs, float* __restrict__ Pksum)
{
    __shared__ float kpL[KVS_TS][MF];
    __shared__ float egL[KVS_TS][KG];
    __shared__ float vL[KVS_TS][KVS_DZ];
    int tid = threadIdx.x;
    int h = blockIdx.y;
    int z = blockIdx.z;
    int d0 = z * KVS_DZ;
    int f32 = *flag;
    int n0 = blockIdx.x * KVS_NPB;
    int ki = tid / MF, mi = tid - ki * MF;   // valid for tid<300
    float4 acc0 = {0, 0, 0, 0}, acc1 = {0, 0, 0, 0}, acc2 = {0, 0, 0, 0}, acc3 = {0, 0, 0, 0};
    float ksacc = 0.f;
    for (int t0 = 0; t0 < KVS_NPB; t0 += KVS_TS) {
        __syncthreads();
        for (int i = tid; i < KVS_TS * MF; i += 320) {          // kp tile (coalesced)
            int j = i / MF, m = i - j * MF;
            kpL[j][m] = kp[(size_t)(n0 + t0 + j) * (NH * MF) + h * MF + m];
        }
        for (int i = tid; i < KVS_TS * KG; i += 320) {          // exp(gumbel) tile
            int j = i / KG, k = i - j * KG;
            size_t gofs = (size_t)(n0 + t0 + j) * (NH * KG) + h * KG + k;
            float g = f32 ? ((const float*)gum)[gofs] : u2f(((const u16*)gum)[gofs]);
            egL[j][k] = expf(g);
        }
        for (int i = tid; i < KVS_TS * KVS_DZ; i += 320) {      // V d-slice tile (bf16)
            int j = i / KVS_DZ, dd = i - j * KVS_DZ;
            vL[j][dd] = u2f(V16[(size_t)(n0 + t0 + j) * 256 + h * 64 + d0 + dd]);
        }
        __syncthreads();
        if (tid < KG * MF) {
            for (int j = 0; j < KVS_TS; ++j) {
                float w = kpL[j][mi] * egL[j][ki];
                ksacc += w;
                const float4* vp = (const float4*)(&vL[j][0]);   // 4x ds_read_b128
                float4 v0 = vp[0], v1 = vp[1], v2 = vp[2], v3 = vp[3];
                acc0.x += w * v0.x; acc0.y += w * v0.y; acc0.z += w * v0.z; acc0.w += w * v0.w;
                acc1.x += w * v1.x; acc1.y += w * v1.y; acc1.z += w * v1.z; acc1.w += w * v1.w;
                acc2.x += w * v2.x; acc2.y += w * v2.y; acc2.z += w * v2.z; acc2.w += w * v2.w;
                acc3.x += w * v3.x; acc3.y += w * v3.y; acc3.z += w * v3.z; acc3.w += w * v3.w;
            }
        }
    }
    if (tid < KG * MF) {
        float4* dst = (float4*)(Pkvs + (((size_t)blockIdx.x * NH + h) * 4 + z) * 4800 + tid * 16);
        dst[0] = acc0; dst[1] = acc1; dst[2] = acc2; dst[3] = acc3;
        if (z == 0) Pksum[blockIdx.x * 1200 + h * 300 + tid] = ksacc;
    }
}

// ---------------- reduce partials -> kvs, ksum ----------------
__global__ __launch_bounds__(256) void k_reduce(const float* __restrict__ Pkvs, const float* __restrict__ Pksum,
                                                float* __restrict__ kvs, float* __restrict__ ksum)
{
    int i = blockIdx.x * 256 + threadIdx.x;
    if (i < NH * KG * MF * DH) {
        int h  = i / (KG * MF * DH);
        int km = (i / DH) % (KG * MF);
        int d  = i & (DH - 1);
        size_t ofs = ((size_t)h * 4 + (d >> 4)) * 4800 + km * 16 + (d & 15);
        float s = 0.f;
        for (int c = 0; c < KVS_CHUNKS; ++c) s += Pkvs[(size_t)c * (NH * 4 * 4800) + ofs];
        kvs[i] = s;
    } else if (i < NH * KG * MF * DH + NH * KG * MF) {
        int j = i - NH * KG * MF * DH;
        float s = 0.f;
        for (int c = 0; c < KVS_CHUNKS; ++c) s += Pksum[c * 1200 + j];
        ksum[j] = s;
    }
}

// ---------------- per-edge attention weights -> link loss partials ----------------
__global__ __launch_bounds__(256) void k_edge(const int* __restrict__ ei,
                                              const u16* __restrict__ qp16, const u16* __restrict__ kp16,
                                              const float* __restrict__ an,
                                              const int* __restrict__ din, float* __restrict__ lossp)
{
    __shared__ float ls[64];
    int tid = threadIdx.x;
    int eg = tid >> 2, h = tid & 3;
    int e = blockIdx.x * 64 + eg;           // grid = NE/64 exact
    int s = ei[e], t = ei[NE + e];
    const uint4* qv = (const uint4*)(qp16 + ((size_t)t * NH + h) * 32);
    const uint4* kv = (const uint4*)(kp16 + ((size_t)s * NH + h) * 32);
    float num = 0.f;
    #pragma unroll
    for (int c = 0; c < 4; ++c) {
        uint4 a = qv[c], b = kv[c];
        num += u2f((u16)(a.x & 0xFFFF)) * u2f((u16)(b.x & 0xFFFF))
             + u2f((u16)(a.x >> 16))    * u2f((u16)(b.x >> 16))
             + u2f((u16)(a.y & 0xFFFF)) * u2f((u16)(b.y & 0xFFFF))
             + u2f((u16)(a.y >> 16))    * u2f((u16)(b.y >> 16))
             + u2f((u16)(a.z & 0xFFFF)) * u2f((u16)(b.z & 0xFFFF))
             + u2f((u16)(a.z >> 16))    * u2f((u16)(b.z >> 16))
             + u2f((u16)(a.w & 0xFFFF)) * u2f((u16)(b.w & 0xFFFF))
             + u2f((u16)(a.w >> 16))    * u2f((u16)(b.w >> 16));
    }
    float term = logf(num / an[(size_t)t * NH + h]);
    term += __shfl_xor(term, 1);
    term += __shfl_xor(term, 2);
    if (h == 0) ls[eg] = term / (float)din[t];
    __syncthreads();
    if (tid < 64) {
        float v = ls[tid];
        #pragma unroll
        for (int o = 32; o > 0; o >>= 1) v += __shfl_xor(v, o);
        if (tid == 0) atomicAdd(&lossp[blockIdx.x & 1023], v);
    }
}

// ---------------- attention readout: 48 nodes/block (3x16 sub-tiles) ----------------
#define AT_NT 48
__global__ __launch_bounds__(256) void k_attn(
    const float* __restrict__ qp, const float* __restrict__ kvs, const float* __restrict__ ksum,
    u16* __restrict__ zatt)
{
    __shared__ float qpTf[3][NH * 484];       // per 16-node sub-tile: plane h [m][j] stride 16
    __shared__ u32   kvbuf[NH * 964];         // bf16 kvs plane (stride 1928 u16); prologue alias: ksL fp32
    __shared__ float rdenL[3][16 * NH * KG];  // [sub][j][h][k]
    u16*   kvL16 = (u16*)kvbuf;
    float* ksL   = (float*)kvbuf;             // 1200 floats, dead before first kv stage
    int tid = threadIdx.x;
    int n0 = blockIdx.x * AT_NT;              // grid = NN/48 = 625 exact

    for (int i = tid; i < AT_NT * NH * MF; i += 256) {   // qp -> transposed LDS
        int j48 = i / (NH * MF); int r = i - j48 * (NH * MF);
        int h = r / MF; int m = r - h * MF;
        qpTf[j48 >> 4][h * 484 + m * 16 + (j48 & 15)] = qp[(size_t)(n0 + j48) * (NH * MF) + r];
    }
    for (int i = tid; i < NH * KG * MF; i += 256) ksL[i] = ksum[i];
    __syncthreads();
    for (int i = tid; i < AT_NT * NH * KG; i += 256) {   // rden = 1/(qp.ksum)
        int j48 = i / (NH * KG); int r = i - j48 * (NH * KG);
        int h = r / KG;
        int sub = j48 >> 4, j = j48 & 15;
        float s = 0.f;
        #pragma unroll
        for (int m = 0; m < MF; ++m) s += qpTf[sub][h * 484 + m * 16 + j] * ksL[r * MF + m];
        rdenL[sub][j * (NH * KG) + r] = 1.0f / s;
    }

    const int h  = tid >> 6;
    const int jg = (tid >> 4) & 3;
    const int dg = tid & 15;
    float acc[3][4][4] = {};
    for (int k = 0; k < KG; ++k) {
        __syncthreads();   // also protects ksL->kvL16 overlay on first iteration
        for (int i = tid; i < NH * MF * DH; i += 256) {  // stage kvs[:,k,:,:] as bf16
            int hh = i / (MF * DH); int r = i - hh * (MF * DH);
            kvL16[hh * 1928 + r] = f2bf(kvs[((size_t)(hh * KG + k) * MF) * DH + r]);
        }
        __syncthreads();
        float ps[3][4][4] = {};
        const u16* kb = kvL16 + h * 1928 + dg * 4;
        const float* qb0 = qpTf[0] + h * 484 + jg * 4;
        const float* qb1 = qpTf[1] + h * 484 + jg * 4;
        const float* qb2 = qpTf[2] + h * 484 + jg * 4;
        #pragma unroll
        for (int m = 0; m < MF; ++m) {
            ushort4 bu = *(const ushort4*)(kb + m * 64);
            float4 b = make_float4(u2f(bu.x), u2f(bu.y), u2f(bu.z), u2f(bu.w));
            float4 a0 = *(const float4*)(qb0 + m * 16);
            float4 a1 = *(const float4*)(qb1 + m * 16);
            float4 a2 = *(const float4*)(qb2 + m * 16);
            ps[0][0][0] += a0.x * b.x; ps[0][0][1] += a0.x * b.y; ps[0][0][2] += a0.x * b.z; ps[0][0][3] += a0.x * b.w;
            ps[0][1][0] += a0.y * b.x; ps[0][1][1] += a0.y * b.y; ps[0][1][2] += a0.y * b.z; ps[0][1][3] += a0.y * b.w;
            ps[0][2][0] += a0.z * b.x; ps[0][2][1] += a0.z * b.y; ps[0][2][2] += a0.z * b.z; ps[0][2][3] += a0.z * b.w;
            ps[0][3][0] += a0.w * b.x; ps[0][3][1] += a0.w * b.y; ps[0][3][2] += a0.w * b.z; ps[0][3][3] += a0.w * b.w;
            ps[1][0][0] += a1.x * b.x; ps[1][0][1] += a1.x * b.y; ps[1][0][2] += a1.x * b.z; ps[1][0][3] += a1.x * b.w;
            ps[1][1][0] += a1.y * b.x; ps[1][1][1] += a1.y * b.y; ps[1][1][2] += a1.y * b.z; ps[1][1][3] += a1.y * b.w;
            ps[1][2][0] += a1.z * b.x; ps[1][2][1] += a1.z * b.y; ps[1][2][2] += a1.z * b.z; ps[1][2][3] += a1.z * b.w;
            ps[1][3][0] += a1.w * b.x; ps[1][3][1] += a1.w * b.y; ps[1][3][2] += a1.w * b.z; ps[1][3][3] += a1.w * b.w;
            ps[2][0][0] += a2.x * b.x; ps[2][0][1] += a2.x * b.y; ps[2][0][2] += a2.x * b.z; ps[2][0][3] += a2.x * b.w;
            ps[2][1][0] += a2.y * b.x; ps[2][1][1] += a2.y * b.y; ps[2][1][2] += a2.y * b.z; ps[2][1][3] += a2.y * b.w;
            ps[2][2][0] += a2.z * b.x; ps[2][2][1] += a2.z * b.y; ps[2][2][2] += a2.z * b.z; ps[2][2][3] += a2.z * b.w;
            ps[2][3][0] += a2.w * b.x; ps[2][3][1] += a2.w * b.y; ps[2][3][2] += a2.w * b.z; ps[2][3][3] += a2.w * b.w;
        }
        #pragma unroll
        for (int sub = 0; sub < 3; ++sub)
            #pragma unroll
            for (int j4 = 0; j4 < 4; ++j4) {
                float rd = rdenL[sub][(jg * 4 + j4) * (NH * KG) + h * KG + k];
                #pragma unroll
                for (int d4 = 0; d4 < 4; ++d4) acc[sub][j4][d4] += ps[sub][j4][d4] * rd;
            }
    }
    #pragma unroll
    for (int sub = 0; sub < 3; ++sub)
        #pragma unroll
        for (int j4 = 0; j4 < 4; ++j4) {
            int n = n0 + sub * 16 + jg * 4 + j4;
            #pragma unroll
            for (int d4 = 0; d4 < 4; ++d4)
                zatt[(size_t)n * 256 + h * 64 + dg * 4 + d4] = f2bf(acc[sub][j4][d4] * (1.0f / KG));
        }
}

// ---------------- conv gather + zatt add + Wo projection ----------------
// Round 15: round-14 structure (16 B/lane uint4, 2 rows/issue, 2-deep unroll,
// full-block Wo matvec) but csr/wedge broadcast via LDS, NOT __shfl. Round-14
// failed because the gather loop bound depends on r=2w+half which differs
// between wave halves -> divergent trip counts -> __shfl (ds_bpermute) read
// from inactive source lanes -> dropped rows. LDS reads are divergence-safe;
// 32 lanes reading the same sIdx[r] is a bank broadcast.
__global__ __launch_bounds__(256) void k_conv(
    const u16* __restrict__ zatt, const u16* __restrict__ V16,
    const int* __restrict__ csr, const float* __restrict__ wedge,
    const int* __restrict__ offn, const int* __restrict__ din,
    const float* __restrict__ params, float* __restrict__ out)
{
    __shared__ float sP[8][32][8];   // [wave*2+half][li][elem]
    __shared__ float sL[256];
    __shared__ int   sIdx[64];
    __shared__ float sW[64];
    __shared__ float sigb[4];
    int n = blockIdx.x, tid = threadIdx.x;
    if (tid < 4) sigb[tid] = 1.f / (1.f + expf(-params[P_BBF + tid]));
    const int w = tid >> 6;
    const int l = tid & 63;
    const int half = l >> 5;
    const int li = l & 31;          // element chunk: c = li*8 .. li*8+7
    int dn = din[n], o0 = offn[n];
    float c0 = 0.f, c1 = 0.f, c2 = 0.f, c3 = 0.f, c4 = 0.f, c5 = 0.f, c6 = 0.f, c7 = 0.f;
    for (int t0 = 0; t0 < dn; t0 += 64) {
        int cnt = min(64, dn - t0);
        __syncthreads();
        if (tid < cnt) { sIdx[tid] = csr[o0 + t0 + tid]; sW[tid] = wedge[o0 + t0 + tid]; }
        __syncthreads();
        int r = 2 * w + half;       // rows for this (wave,half): r, r+8, r+16, ...
        for (; r + 8 < cnt; r += 16) {   // 2-deep: rows r and r+8 in flight
            int   s0 = sIdx[r];  int   s1 = sIdx[r + 8];
            float w0 = sW[r];    float w1 = sW[r + 8];
            uint4 va = *(const uint4*)(V16 + (size_t)s0 * 256 + li * 8);
            uint4 vb = *(const uint4*)(V16 + (size_t)s1 * 256 + li * 8);
            c0 += w0 * u2f((u16)(va.x & 0xFFFF)) + w1 * u2f((u16)(vb.x & 0xFFFF));
            c1 += w0 * u2f((u16)(va.x >> 16))    + w1 * u2f((u16)(vb.x >> 16));
            c2 += w0 * u2f((u16)(va.y & 0xFFFF)) + w1 * u2f((u16)(vb.y & 0xFFFF));
            c3 += w0 * u2f((u16)(va.y >> 16))    + w1 * u2f((u16)(vb.y >> 16));
            c4 += w0 * u2f((u16)(va.z & 0xFFFF)) + w1 * u2f((u16)(vb.z & 0xFFFF));
            c5 += w0 * u2f((u16)(va.z >> 16))    + w1 * u2f((u16)(vb.z >> 16));
            c6 += w0 * u2f((u16)(va.w & 0xFFFF)) + w1 * u2f((u16)(vb.w & 0xFFFF));
            c7 += w0 * u2f((u16)(va.w >> 16))    + w1 * u2f((u16)(vb.w >> 16));
        }
        if (r < cnt) {
            int   s0 = sIdx[r];
            float w0 = sW[r];
            uint4 va = *(const uint4*)(V16 + (size_t)s0 * 256 + li * 8);
            c0 += w0 * u2f((u16)(va.x & 0xFFFF));
            c1 += w0 * u2f((u16)(va.x >> 16));
            c2 += w0 * u2f((u16)(va.y & 0xFFFF));
            c3 += w0 * u2f((u16)(va.y >> 16));
            c4 += w0 * u2f((u16)(va.z & 0xFFFF));
            c5 += w0 * u2f((u16)(va.z >> 16));
            c6 += w0 * u2f((u16)(va.w & 0xFFFF));
            c7 += w0 * u2f((u16)(va.w >> 16));
        }
    }
    {
        int g = w * 2 + half;
        *(float4*)&sP[g][li][0] = make_float4(c0, c1, c2, c3);
        *(float4*)&sP[g][li][4] = make_float4(c4, c5, c6, c7);
    }
    __syncthreads();
    {   // conv element tid: sum 8 partials; fold in zatt + sigmoid bias
        float conv = 0.f;
        #pragma unroll
        for (int g2 = 0; g2 < 8; ++g2) conv += sP[g2][tid >> 3][tid & 7];
        sL[tid] = u2f(zatt[(size_t)n * 256 + tid]) + sigb[tid >> 6] * conv;
    }
    __syncthreads();
    {   // Wo matvec: thread (o=tid>>2, q=tid&3) -> 64-wide partial + shfl tree
        int o = tid >> 2, q = tid & 3;
        const float4* wr = (const float4*)(params + P_WOF + (size_t)o * 256 + q * 64);
        const float* sp = sL + q * 64;
        float acc2 = 0.f;
        #pragma unroll
        for (int c4i = 0; c4i < 16; ++c4i) {
            float4 u = wr[c4i];
            acc2 += u.x * sp[c4i * 4] + u.y * sp[c4i * 4 + 1] + u.z * sp[c4i * 4 + 2] + u.w * sp[c4i * 4 + 3];
        }
        acc2 += __shfl_xor(acc2, 1);
        acc2 += __shfl_xor(acc2, 2);
        if (q == 0) out[(size_t)n * 64 + o] = acc2 + params[P_WOBF + o];
    }
}

// ---------------- loss finalize ----------------
__global__ __launch_bounds__(256) void k_loss(const float* __restrict__ lossp, float* __restrict__ out) {
    __shared__ float s[256];
    int tid = threadIdx.x;
    float v = 0.f;
    for (int i = tid; i < 1024; i += 256) v += lossp[i];
    s[tid] = v;
    __syncthreads();
    for (int o = 128; o > 0; o >>= 1) {
        if (tid < o) s[tid] += s[tid + o];
        __syncthreads();
    }
    if (tid == 0) out[(size_t)NN * 64] = s[0] / (float)(NE * NH);   // fp32 output
}

extern "C" void kernel_launch(void* const* d_in, const int* in_sizes, int n_in,
                              void* d_out, int out_size, void* d_ws, size_t ws_size,
                              hipStream_t stream)
{
    const void* z    = d_in[0];
    const int*  ei   = (const int*)d_in[1];
    const void* taup = d_in[2];
    const void* gum  = d_in[3];
    const void* proj = d_in[4];
    const void* Wq   = d_in[5];
    const void* bq   = d_in[6];
    const void* Wk   = d_in[7];
    const void* bk   = d_in[8];
    const void* Wv   = d_in[9];
    const void* bv   = d_in[10];
    const void* Wo   = d_in[11];
    const void* Wob  = d_in[12];
    const void* bb   = d_in[13];
    float* out = (float*)d_out;

    // ---- workspace carve-up (fp32 units), total ~67 MB ----
    u16*   V16    = (u16*)d_ws;                    //  7,680,000 u16 : [N,256] bf16 V
    float* qpb    = (float*)d_ws + 3840000;        //  3,600,000 : [N,H,M]
    float* kpb    = qpb + (size_t)NN * NH * MF;    //  3,600,000 : dashK then kp in-place
    float* diagK  = kpb + (size_t)NN * NH * MF;    //    120,000
    float* anb    = diagK + (size_t)NN * NH;       //    120,000
    u16*   zatt   = (u16*)kpb;                     //  reuses kpb+diagK+anb (dead after k_edge)
    int*   csr    = (int*)(anb + (size_t)NN * NH); //    480,000
    int*   offn   = csr + NE;                      //     30,000
    float* params = (float*)(offn + NN);           //    215,749 (+pad to 215,752)
    // ---- zeroed accumulator region ----
    float* kvs    = params + 215752;               //     76,800 : [H,K,M,D]
    float* ksum   = kvs + NH * KG * MF * DH;       //      1,200 : [H,K,M]
    float* kpsum  = ksum + NH * KG * MF;           //        120 : [H,M]
    int*   din    = (int*)(kpsum + NH * MF);       //     30,000
    int*   doutd  = din + NN;                      //     30,000
    int*   fill   = doutd + NN;                    //     30,000
    int*   counter = fill + NN;                    //          4
    u32*   stab   = (u32*)(counter + 4);           //          4
    float* lossp  = (float*)(stab + 4);            //      1,024
    int*   flag   = (int*)(lossp + 1024);          //          4
    float* wedge  = (float*)(flag + 4);            //    480,000 (not zeroed; fully written)
    u16*   qp16   = (u16*)(wedge + NE);            //  3,840,000 u16 : [N,H,32] bf16 qp
    u16*   kp16   = qp16 + (size_t)NN * NH * 32;   //  3,840,000 u16 : [N,H,32] bf16 kp
    // kvs partials overlay qp16+kp16 (15.36 MB, exact fit: 50*4*4*4800 floats);
    // alive only between k_kvs and k_reduce, after qp16/kp16's last reader (k_edge).
    float* Pkvs   = (float*)qp16;
    float* Pksum  = (float*)(kp16 + (size_t)NN * NH * 32);   //  60,000 floats (new tail)
    // W hi/lo bf16 planes overlay kp16 (dead until k_kp writes it, after k_gemm_feat)
    u16*   Whb    = kp16;                          //    196,608 u16 : [768][256] W hi
    u16*   Wlb    = kp16 + 196608;                 //    196,608 u16 : [768][256] W lo
    size_t zero_bytes = (size_t)((char*)(flag + 4) - (char*)kvs);

    hipMemsetAsync(kvs, 0, zero_bytes, stream);

    k_detect<<<dim3(1), dim3(64), 0, stream>>>((const u16*)z, flag);
    k_cvt_params<<<dim3((P_TOTAL + 255) / 256), dim3(256), 0, stream>>>(
        Wq, Wk, Wv, bq, bk, bv, Wo, Wob, bb, proj, taup, params, flag);
    k_cvt_w<<<dim3(768), dim3(256), 0, stream>>>(params, Whb, Wlb);

    k_deg <<<dim3((NE + 255) / 256), dim3(256), 0, stream>>>(ei, din, doutd);
    k_off <<<dim3((NN + 255) / 256), dim3(256), 0, stream>>>(din, offn, counter);
    k_fill<<<dim3((NE + 255) / 256), dim3(256), 0, stream>>>(ei, offn, fill, csr, din, doutd, wedge);
    k_gemm_feat<<<dim3((NN + 63) / 64, 12), dim3(256), 0, stream>>>(
        z, params, flag, Whb, Wlb, V16, qpb, qp16, kpb, diagK, stab);
    k_kp  <<<dim3(NN * NH / 64), dim3(256), 0, stream>>>(kpb, diagK, stab, kpsum, kp16);
    k_an  <<<dim3((NN * NH + 255) / 256), dim3(256), 0, stream>>>(qpb, kpsum, anb);
    k_edge<<<dim3(NE / 64), dim3(256), 0, stream>>>(ei, qp16, kp16, anb, din, lossp);
    // qp16/kp16 dead from here; Pkvs overlays them (stream-ordered)
    k_kvs <<<dim3(KVS_CHUNKS, NH, DH / KVS_DZ), dim3(320), 0, stream>>>(kpb, gum, V16, flag, Pkvs, Pksum);
    k_reduce<<<dim3((NH * KG * MF * DH + NH * KG * MF + 255) / 256), dim3(256), 0, stream>>>(
        Pkvs, Pksum, kvs, ksum);
    // zatt overwrites kpb/diagK/anb from here on (stream-ordered after their last readers)
    k_attn<<<dim3(NN / AT_NT), dim3(256), 0, stream>>>(qpb, kvs, ksum, zatt);
    k_conv<<<dim3(NN), dim3(256), 0, stream>>>(zatt, V16, csr, wedge, offn, din, params, out);
    k_loss<<<dim3(1), dim3(256), 0, stream>>>(lossp, out);
}

// Round 4
// 762.377 us; speedup vs baseline: 1.3026x; 1.3026x over previous
//
#include <hip/hip_runtime.h>
#include <hip/hip_bf16.h>

#define NN 30000
#define NE 480000
#define NH 4
#define DH 64
#define MF 30
#define KG 10
#define RATIO 0.18257418583505536f   /* 1/sqrt(30) */
#define DNRM  0.35355339059327373f   /* 64^-0.25  */

// fp32 params block layout (element offsets)
#define P_WF    0        /* [768][256] Wq|Wk|Wv rows */
#define P_BF    196608   /* [768] bq|bk|bv */
#define P_WOF   197376   /* [64][256] Wo */
#define P_WOBF  213760   /* [64] Wo bias */
#define P_BBF   213824   /* [4] rb bias b */
#define P_PROJ  213828   /* [30][64] proj */
#define P_TAU   215748   /* scalar */
#define P_TOTAL 215749

typedef unsigned short u16;
typedef unsigned int   u32;
typedef __attribute__((ext_vector_type(8))) short bf16x8;
typedef __attribute__((ext_vector_type(4))) float f32x4;

__device__ __forceinline__ float u2f(u16 u) { return __uint_as_float(((u32)u) << 16); }
__device__ __forceinline__ u16  f2bf(float f) {  // round-to-nearest-even bf16
    u32 x = __float_as_uint(f);
    return (u16)((x + 0x7FFFu + ((x >> 16) & 1u)) >> 16);
}
// order-preserving float->uint encoding for atomicMax over signed floats
__device__ __forceinline__ u32  encf(float f) { u32 u = __float_as_uint(f); return (u & 0x80000000u) ? ~u : (u | 0x80000000u); }
__device__ __forceinline__ float decf(u32 u)  { return (u & 0x80000000u) ? __uint_as_float(u & 0x7FFFFFFFu) : __uint_as_float(~u); }

// ---------------- dtype detection (fp32 vs bf16 input tensors) ----------------
__global__ void k_detect(const u16* __restrict__ z, int* __restrict__ flag) {
    if (threadIdx.x == 0 && blockIdx.x == 0) {
        int bad = 0;
        for (int i = 0; i < 256; i += 2) {
            u16 u = z[i];
            int e = (u >> 7) & 0xFF;
            if (u != 0 && !(e >= 100 && e <= 140)) bad++;
        }
        *flag = (bad > 16) ? 1 : 0;   // 1 = inputs are fp32
    }
}

// ---------------- stage all small params to fp32 ----------------
__global__ __launch_bounds__(256) void k_cvt_params(
    const void* Wq, const void* Wk, const void* Wv,
    const void* bq, const void* bk, const void* bv,
    const void* Wo, const void* Wob, const void* bb, const void* proj,
    const void* taup, float* __restrict__ params, const int* __restrict__ flag)
{
    int i = blockIdx.x * 256 + threadIdx.x;
    if (i >= P_TOTAL) return;
    int f = *flag;
    if (i == P_TAU) {
        float v = f ? ((const float*)taup)[0] : u2f(((const u16*)taup)[0]);
        if (!(v > 1e-6f && v < 1e6f)) {
            float ff = ((const float*)taup)[0];
            v = (ff > 1e-6f && ff < 1e6f) ? ff : 0.25f;
        }
        params[i] = v;
        return;
    }
    const void* src; int j;
    if      (i < 65536)  { src = Wq;  j = i; }
    else if (i < 131072) { src = Wk;  j = i - 65536; }
    else if (i < 196608) { src = Wv;  j = i - 131072; }
    else if (i < 196864) { src = bq;  j = i - 196608; }
    else if (i < 197120) { src = bk;  j = i - 196864; }
    else if (i < 197376) { src = bv;  j = i - 197120; }
    else if (i < 213760) { src = Wo;  j = i - 197376; }
    else if (i < 213824) { src = Wob; j = i - 213760; }
    else if (i < 213828) { src = bb;  j = i - 213824; }
    else                 { src = proj; j = i - P_PROJ; }
    params[i] = f ? ((const float*)src)[j] : u2f(((const u16*)src)[j]);
}

// ---------------- hi/lo bf16 split of W (once; gemm staging becomes pure copy) ----------------
__global__ __launch_bounds__(256) void k_cvt_w(const float* __restrict__ params,
                                               u16* __restrict__ Wh, u16* __restrict__ Wl)
{
    int i = blockIdx.x * 256 + threadIdx.x;   // grid = 768 blocks, 196608 exact
    float x = params[P_WF + i];
    u16 h = f2bf(x);
    Wh[i] = h;
    Wl[i] = f2bf(x - u2f(h));
}

// ---------------- degrees ----------------
__global__ __launch_bounds__(256) void k_deg(const int* __restrict__ ei, int* __restrict__ din, int* __restrict__ dout) {
    int e = blockIdx.x * 256 + threadIdx.x;
    if (e >= NE) return;
    atomicAdd(&dout[ei[e]], 1);
    atomicAdd(&din[ei[NE + e]], 1);
}

// ---------------- scan-free CSR offsets ----------------
__global__ __launch_bounds__(256) void k_off(const int* __restrict__ din, int* __restrict__ offn, int* __restrict__ counter) {
    __shared__ int s[256];
    __shared__ int base;
    int tid = threadIdx.x;
    int n = blockIdx.x * 256 + tid;
    int v = (n < NN) ? din[n] : 0;
    s[tid] = v;
    __syncthreads();
    for (int o = 1; o < 256; o <<= 1) {
        int t = (tid >= o) ? s[tid - o] : 0;
        __syncthreads();
        s[tid] += t;
        __syncthreads();
    }
    if (tid == 255) base = atomicAdd(counter, s[255]);
    __syncthreads();
    if (n < NN) offn[n] = base + s[tid] - v;
}

// fill CSR + precompute per-edge conv weight w = rsqrt(din[t]*dout[s])
__global__ __launch_bounds__(256) void k_fill(const int* __restrict__ ei, const int* __restrict__ offn,
                                              int* __restrict__ fill, int* __restrict__ csr,
                                              const int* __restrict__ din, const int* __restrict__ dout,
                                              float* __restrict__ wedge) {
    int e = blockIdx.x * 256 + threadIdx.x;
    if (e >= NE) return;
    int s = ei[e], t = ei[NE + e];
    int pos = offn[t] + atomicAdd(&fill[t], 1);
    csr[pos] = s;
    wedge[pos] = rsqrtf((float)din[t] * (float)dout[s]);
}

// ---------------- fused QKV GEMM (bf16 MFMA, hi/lo split) + Performer epilogue ----------------
// grid (ceil(NN/64), 12): y 0..3 -> Q head y; y 4..7 -> K head y-4; y 8..11 -> V cols.
// fp32 inputs: A,B split into hi+lo bf16 planes; C = Ah*Bh + Ah*Bl + Al*Bh (3 MFMA passes,
// rel err ~2^-17 -- below the bf16 noise already accepted downstream). bf16 inputs: 1 exact pass.
// LDS planes are 128B-row tiles with T2 XOR swizzle (byte ^= (row&7)<<4) on write AND read.
__global__ __launch_bounds__(256) void k_gemm_feat(
    const void* __restrict__ zv, const float* __restrict__ params, const int* __restrict__ flag,
    const u16* __restrict__ Wh, const u16* __restrict__ Wl,
    u16* __restrict__ V16, float* __restrict__ qp, u16* __restrict__ qp16,
    float* __restrict__ dashK, float* __restrict__ diagK, u32* __restrict__ stab)
{
    __shared__ __align__(16) char smemc[32768];  // 4 bf16 planes of 64x64 (8 KB each)
    __shared__ u32 smaxL;
    char* AsH = smemc;                // A hi plane
    char* AsL = smemc + 8192;         // A lo plane
    char* BsH = smemc + 16384;        // B hi plane
    char* BsL = smemc + 24576;        // B lo plane
    float* tile  = (float*)smemc;          // 64 x 68 fp32 epilogue tile (overlays planes)
    float* projL = (float*)smemc + 4352;   // 30 x 65 (overlays planes; staged after GEMM)

    const int tid = threadIdx.x;
    const int bm = blockIdx.x * 64;
    const int bn = blockIdx.y * 64;
    const int f32 = *flag;
    const int wave = tid >> 6, lane = tid & 63;
    const int wm = wave >> 1, wn = wave & 1;     // 2x2 wave grid, each wave 32x32
    const int sr = tid >> 2;                     // staging row 0..63
    const int sc = (tid & 3) * 16;               // staging col base (16 cols/thread/chunk)

    f32x4 acc[2][2] = {};

    for (int k0 = 0; k0 < 256; k0 += 64) {
        __syncthreads();
        // ---------- stage A (z), hi/lo split on the fly ----------
        {
            int zrow = bm + sr;
            if (f32) {
                float x[16];
                if (zrow < NN) {
                    const float4* zp = (const float4*)((const float*)zv + (size_t)zrow * 256 + k0 + sc);
                    #pragma unroll
                    for (int q4 = 0; q4 < 4; ++q4) {
                        float4 v = zp[q4];
                        x[q4 * 4 + 0] = v.x; x[q4 * 4 + 1] = v.y;
                        x[q4 * 4 + 2] = v.z; x[q4 * 4 + 3] = v.w;
                    }
                } else {
                    #pragma unroll
                    for (int j = 0; j < 16; ++j) x[j] = 0.f;
                }
                #pragma unroll
                for (int j8 = 0; j8 < 2; ++j8) {
                    u32 hw[4], lw[4];
                    #pragma unroll
                    for (int p = 0; p < 4; ++p) {
                        float a = x[j8 * 8 + 2 * p], b2 = x[j8 * 8 + 2 * p + 1];
                        u16 ha = f2bf(a), hb = f2bf(b2);
                        hw[p] = (u32)ha | ((u32)hb << 16);
                        u16 la = f2bf(a - u2f(ha)), lb = f2bf(b2 - u2f(hb));
                        lw[p] = (u32)la | ((u32)lb << 16);
                    }
                    int byt = sr * 128 + (((sc + j8 * 8) * 2) ^ ((sr & 7) << 4));
                    *(uint4*)(AsH + byt) = make_uint4(hw[0], hw[1], hw[2], hw[3]);
                    *(uint4*)(AsL + byt) = make_uint4(lw[0], lw[1], lw[2], lw[3]);
                }
            } else {
                uint4 v0 = make_uint4(0, 0, 0, 0), v1 = v0;
                if (zrow < NN) {
                    const uint4* zp = (const uint4*)((const u16*)zv + (size_t)zrow * 256 + k0 + sc);
                    v0 = zp[0]; v1 = zp[1];
                }
                int byt0 = sr * 128 + (((sc + 0) * 2) ^ ((sr & 7) << 4));
                int byt1 = sr * 128 + (((sc + 8) * 2) ^ ((sr & 7) << 4));
                *(uint4*)(AsH + byt0) = v0;
                *(uint4*)(AsH + byt1) = v1;
            }
        }
        // ---------- stage B (preconverted W hi/lo: pure copy) ----------
        {
            int byt0 = sr * 128 + (((sc + 0) * 2) ^ ((sr & 7) << 4));
            int byt1 = sr * 128 + (((sc + 8) * 2) ^ ((sr & 7) << 4));
            const uint4* wh4 = (const uint4*)(Wh + (size_t)(bn + sr) * 256 + k0 + sc);
            *(uint4*)(BsH + byt0) = wh4[0];
            *(uint4*)(BsH + byt1) = wh4[1];
            if (f32) {
                const uint4* wl4 = (const uint4*)(Wl + (size_t)(bn + sr) * 256 + k0 + sc);
                *(uint4*)(BsL + byt0) = wl4[0];
                *(uint4*)(BsL + byt1) = wl4[1];
            }
        }
        __syncthreads();
        // ---------- MFMA: 2 k-steps of 32 per chunk ----------
        #pragma unroll
        for (int kk = 0; kk < 2; ++kk) {
            const int kb = (kk * 32 + ((lane >> 4) * 8)) * 2;   // byte col of this lane's 8 k-elems
            bf16x8 ah[2], bh[2], al[2], bl[2];
            #pragma unroll
            for (int i = 0; i < 2; ++i) {
                int ar = 32 * wm + 16 * i + (lane & 15);
                int ab = ar * 128 + (kb ^ ((ar & 7) << 4));
                ah[i] = *(const bf16x8*)(AsH + ab);
                int br = 32 * wn + 16 * i + (lane & 15);
                int bb2 = br * 128 + (kb ^ ((br & 7) << 4));
                bh[i] = *(const bf16x8*)(BsH + bb2);
                if (f32) {
                    al[i] = *(const bf16x8*)(AsL + ab);
                    bl[i] = *(const bf16x8*)(BsL + bb2);
                }
            }
            #pragma unroll
            for (int i = 0; i < 2; ++i)
                #pragma unroll
                for (int nf = 0; nf < 2; ++nf) {
                    acc[i][nf] = __builtin_amdgcn_mfma_f32_16x16x32_bf16(ah[i], bh[nf], acc[i][nf], 0, 0, 0);
                    if (f32) {
                        acc[i][nf] = __builtin_amdgcn_mfma_f32_16x16x32_bf16(ah[i], bl[nf], acc[i][nf], 0, 0, 0);
                        acc[i][nf] = __builtin_amdgcn_mfma_f32_16x16x32_bf16(al[i], bh[nf], acc[i][nf], 0, 0, 0);
                    }
                }
        }
    }
    __syncthreads();   // all plane reads done; smem reusable as tile/projL

    const float* bfv = params + P_BF;
    if (bn >= 512) {   // ---- V: acc -> tile (+bias) -> coalesced bf16 store ----
        #pragma unroll
        for (int i = 0; i < 2; ++i)
            #pragma unroll
            for (int nf = 0; nf < 2; ++nf) {
                int col = 32 * wn + 16 * nf + (lane & 15);
                float bias = bfv[bn + col];
                #pragma unroll
                for (int r2 = 0; r2 < 4; ++r2) {
                    int row = 32 * wm + 16 * i + ((lane >> 4) * 4) + r2;
                    tile[row * 68 + col] = acc[i][nf][r2] + bias;
                }
            }
        __syncthreads();
        for (int i2 = tid; i2 < 4096; i2 += 256) {
            int row = i2 >> 6, col = i2 & 63;
            int nrow = bm + row;
            if (nrow < NN) V16[(size_t)nrow * 256 + (bn - 512) + col] = f2bf(tile[row * 68 + col]);
        }
        return;
    }

    // ---- Q/K: performer features on the 64x64 head tile ----
    for (int i2 = tid; i2 < MF * DH; i2 += 256) projL[(i2 >> 6) * 65 + (i2 & 63)] = params[P_PROJ + i2];
    if (tid == 0) smaxL = 0u;
    float scale = DNRM * rsqrtf(params[P_TAU]);
    #pragma unroll
    for (int i = 0; i < 2; ++i)
        #pragma unroll
        for (int nf = 0; nf < 2; ++nf) {
            int col = 32 * wn + 16 * nf + (lane & 15);
            float bias = bfv[bn + col];
            #pragma unroll
            for (int r2 = 0; r2 < 4; ++r2) {
                int row = 32 * wm + 16 * i + ((lane >> 4) * 4) + r2;
                tile[row * 68 + col] = (acc[i][nf][r2] + bias) * scale;
            }
        }
    __syncthreads();

    int r = tid >> 2, q = tid & 3;      // 4 lanes cooperate per row; same wave
    int n = bm + r;
    const float* trow = tile + r * 68;
    float dp = 0.f;
    #pragma unroll
    for (int d = q * 16; d < q * 16 + 16; ++d) dp += trow[d] * trow[d];
    dp += __shfl_xor(dp, 1);
    dp += __shfl_xor(dp, 2);
    float diag = dp * 0.5f;

    float dm[8];
    int nm = 0;
    float lmax = -3.0e38f;
    for (int m = q; m < MF; m += 4) {
        float s = 0.f;
        #pragma unroll
        for (int d = 0; d < DH; ++d) s += trow[d] * projL[m * 65 + d];
        dm[nm++] = s;
        lmax = fmaxf(lmax, s);
    }
    float mx = fmaxf(lmax, __shfl_xor(lmax, 1));
    mx = fmaxf(mx, __shfl_xor(mx, 2));

    if (bn < 256) {   // Q: row-local stab, write qp (fp32) + packed bf16 copy
        int h = blockIdx.y;
        if (n < NN) {
            float* o = qp + ((size_t)n * NH + h) * MF;
            u16* o16 = qp16 + ((size_t)n * NH + h) * 32;
            nm = 0;
            for (int m = q; m < MF; m += 4) {
                float v = RATIO * (expf(dm[nm++] - diag - mx) + 1e-6f);
                o[m] = v;
                o16[m] = f2bf(v);
            }
            if (q == 0) { o16[30] = 0; o16[31] = 0; }
        }
    } else {          // K: store dash/diag, global per-head max
        int h = blockIdx.y - 4;
        if (n < NN) {
            float* o = dashK + ((size_t)n * NH + h) * MF;
            nm = 0;
            for (int m = q; m < MF; m += 4) o[m] = dm[nm++];
            if (q == 0) {
                diagK[(size_t)n * NH + h] = diag;
                atomicMax(&smaxL, encf(mx));
            }
        }
        __syncthreads();
        if (tid == 0) atomicMax(&stab[h], smaxL);
    }
}

// ---------------- keys pass 2: kp in-place + kpsum + packed bf16 copy ----------------
__global__ __launch_bounds__(256) void k_kp(float* __restrict__ kp, const float* __restrict__ diagK,
                                            const u32* __restrict__ stab, float* __restrict__ kpsum,
                                            u16* __restrict__ kp16)
{
    __shared__ float part[NH * MF];
    __shared__ float stabf[4];
    int tid = threadIdx.x;
    if (tid < NH * MF) part[tid] = 0.f;
    if (tid >= 128 && tid < 132) stabf[tid - 128] = decf(stab[tid - 128]);
    __syncthreads();
    int base = blockIdx.x * 64 * MF;   // 64 rows/block, exact: 1875*64 = 120000
    for (int i = tid; i < 64 * MF; i += 256) {
        int row = blockIdx.x * 64 + i / MF;
        int m = i - (i / MF) * MF;
        int h = row & 3;
        float v = RATIO * (expf(kp[base + i] - diagK[row] - stabf[h]) + 1e-6f);
        kp[base + i] = v;
        kp16[(size_t)row * 32 + m] = f2bf(v);
        atomicAdd(&part[h * MF + m], v);
    }
    if (tid < 64) {
        int row = blockIdx.x * 64 + tid;
        kp16[(size_t)row * 32 + 30] = 0;
        kp16[(size_t)row * 32 + 31] = 0;
    }
    __syncthreads();
    if (tid < NH * MF) atomicAdd(&kpsum[tid], part[tid]);
}

// ---------------- attn_norm[n,h] = qp[n,h,:] . kpsum[h,:] ----------------
__global__ __launch_bounds__(256) void k_an(const float* __restrict__ qp, const float* __restrict__ kpsum,
                                            float* __restrict__ an)
{
    __shared__ float kps[NH * MF];
    int tid = threadIdx.x;
    if (tid < NH * MF) kps[tid] = kpsum[tid];
    __syncthreads();
    int idx = blockIdx.x * 256 + tid;
    if (idx >= NN * NH) return;
    int h = idx & 3;
    const float* q = qp + (size_t)idx * MF;
    float s = 0.f;
    #pragma unroll
    for (int m = 0; m < MF; ++m) s += q[m] * kps[h * MF + m];
    an[idx] = s;
}

// ---------------- kvs partial reduction over nodes (two-stage, NO atomics) ----------------
#define KVS_CHUNKS 50
#define KVS_NPB (NN / KVS_CHUNKS)    /* 600 nodes per block */
#define KVS_TS 40                    /* nodes per LDS tile */
#define KVS_DZ 16                    /* d-slice width, grid.z = DH/KVS_DZ = 4 */
__global__ __launch_bounds__(320) void k_kvs(const float* __restrict__ kp, const void* __restrict__ gum,
                                             const u16* __restrict__ V16, const int* __restrict__ flag,
                                             float* __restrict__ Pkvs, float* __restrict__ Pksum)
{
    __shared__ float kpL[KVS_TS][MF];
    __shared__ float egL[KVS_TS][KG];
    __shared__ float vL[KVS_TS][KVS_DZ];
    int tid = threadIdx.x;
    int h = blockIdx.y;
    int z = blockIdx.z;
    int d0 = z * KVS_DZ;
    int f32 = *flag;
    int n0 = blockIdx.x * KVS_NPB;
    int ki = tid / MF, mi = tid - ki * MF;   // valid for tid<300
    float4 acc0 = {0, 0, 0, 0}, acc1 = {0, 0, 0, 0}, acc2 = {0, 0, 0, 0}, acc3 = {0, 0, 0, 0};
    float ksacc = 0.f;
    for (int t0 = 0; t0 < KVS_NPB; t0 += KVS_TS) {
        __syncthreads();
        for (int i = tid; i < KVS_TS * MF; i += 320) {          // kp tile (coalesced)
            int j = i / MF, m = i - j * MF;
            kpL[j][m] = kp[(size_t)(n0 + t0 + j) * (NH * MF) + h * MF + m];
        }
        for (int i = tid; i < KVS_TS * KG; i += 320) {          // exp(gumbel) tile
            int j = i / KG, k = i - j * KG;
            size_t gofs = (size_t)(n0 + t0 + j) * (NH * KG) + h * KG + k;
            float g = f32 ? ((const float*)gum)[gofs] : u2f(((const u16*)gum)[gofs]);
            egL[j][k] = expf(g);
        }
        for (int i = tid; i < KVS_TS * KVS_DZ; i += 320) {      // V d-slice tile (bf16)
            int j = i / KVS_DZ, dd = i - j * KVS_DZ;
            vL[j][dd] = u2f(V16[(size_t)(n0 + t0 + j) * 256 + h * 64 + d0 + dd]);
        }
        __syncthreads();
        if (tid < KG * MF) {
            for (int j = 0; j < KVS_TS; ++j) {
                float w = kpL[j][mi] * egL[j][ki];
                ksacc += w;
                const float4* vp = (const float4*)(&vL[j][0]);   // 4x ds_read_b128
                float4 v0 = vp[0], v1 = vp[1], v2 = vp[2], v3 = vp[3];
                acc0.x += w * v0.x; acc0.y += w * v0.y; acc0.z += w * v0.z; acc0.w += w * v0.w;
                acc1.x += w * v1.x; acc1.y += w * v1.y; acc1.z += w * v1.z; acc1.w += w * v1.w;
                acc2.x += w * v2.x; acc2.y += w * v2.y; acc2.z += w * v2.z; acc2.w += w * v2.w;
                acc3.x += w * v3.x; acc3.y += w * v3.y; acc3.z += w * v3.z; acc3.w += w * v3.w;
            }
        }
    }
    if (tid < KG * MF) {
        float4* dst = (float4*)(Pkvs + (((size_t)blockIdx.x * NH + h) * 4 + z) * 4800 + tid * 16);
        dst[0] = acc0; dst[1] = acc1; dst[2] = acc2; dst[3] = acc3;
        if (z == 0) Pksum[blockIdx.x * 1200 + h * 300 + tid] = ksacc;
    }
}

// ---------------- reduce partials -> kvs, ksum ----------------
__global__ __launch_bounds__(256) void k_reduce(const float* __restrict__ Pkvs, const float* __restrict__ Pksum,
                                                float* __restrict__ kvs, float* __restrict__ ksum)
{
    int i = blockIdx.x * 256 + threadIdx.x;
    if (i < NH * KG * MF * DH) {
        int h  = i / (KG * MF * DH);
        int km = (i / DH) % (KG * MF);
        int d  = i & (DH - 1);
        size_t ofs = ((size_t)h * 4 + (d >> 4)) * 4800 + km * 16 + (d & 15);
        float s = 0.f;
        for (int c = 0; c < KVS_CHUNKS; ++c) s += Pkvs[(size_t)c * (NH * 4 * 4800) + ofs];
        kvs[i] = s;
    } else if (i < NH * KG * MF * DH + NH * KG * MF) {
        int j = i - NH * KG * MF * DH;
        float s = 0.f;
        for (int c = 0; c < KVS_CHUNKS; ++c) s += Pksum[c * 1200 + j];
        ksum[j] = s;
    }
}

// ---------------- per-edge attention weights -> link loss partials ----------------
__global__ __launch_bounds__(256) void k_edge(const int* __restrict__ ei,
                                              const u16* __restrict__ qp16, const u16* __restrict__ kp16,
                                              const float* __restrict__ an,
                                              const int* __restrict__ din, float* __restrict__ lossp)
{
    __shared__ float ls[64];
    int tid = threadIdx.x;
    int eg = tid >> 2, h = tid & 3;
    int e = blockIdx.x * 64 + eg;           // grid = NE/64 exact
    int s = ei[e], t = ei[NE + e];
    const uint4* qv = (const uint4*)(qp16 + ((size_t)t * NH + h) * 32);
    const uint4* kv = (const uint4*)(kp16 + ((size_t)s * NH + h) * 32);
    float num = 0.f;
    #pragma unroll
    for (int c = 0; c < 4; ++c) {
        uint4 a = qv[c], b = kv[c];
        num += u2f((u16)(a.x & 0xFFFF)) * u2f((u16)(b.x & 0xFFFF))
             + u2f((u16)(a.x >> 16))    * u2f((u16)(b.x >> 16))
             + u2f((u16)(a.y & 0xFFFF)) * u2f((u16)(b.y & 0xFFFF))
             + u2f((u16)(a.y >> 16))    * u2f((u16)(b.y >> 16))
             + u2f((u16)(a.z & 0xFFFF)) * u2f((u16)(b.z & 0xFFFF))
             + u2f((u16)(a.z >> 16))    * u2f((u16)(b.z >> 16))
             + u2f((u16)(a.w & 0xFFFF)) * u2f((u16)(b.w & 0xFFFF))
             + u2f((u16)(a.w >> 16))    * u2f((u16)(b.w >> 16));
    }
    float term = logf(num / an[(size_t)t * NH + h]);
    term += __shfl_xor(term, 1);
    term += __shfl_xor(term, 2);
    if (h == 0) ls[eg] = term / (float)din[t];
    __syncthreads();
    if (tid < 64) {
        float v = ls[tid];
        #pragma unroll
        for (int o = 32; o > 0; o >>= 1) v += __shfl_xor(v, o);
        if (tid == 0) atomicAdd(&lossp[blockIdx.x & 1023], v);
    }
}

// ---------------- attention readout: 48 nodes/block (3x16 sub-tiles) ----------------
#define AT_NT 48
__global__ __launch_bounds__(256) void k_attn(
    const float* __restrict__ qp, const float* __restrict__ kvs, const float* __restrict__ ksum,
    u16* __restrict__ zatt)
{
    __shared__ float qpTf[3][NH * 484];       // per 16-node sub-tile: plane h [m][j] stride 16
    __shared__ u32   kvbuf[NH * 964];         // bf16 kvs plane (stride 1928 u16); prologue alias: ksL fp32
    __shared__ float rdenL[3][16 * NH * KG];  // [sub][j][h][k]
    u16*   kvL16 = (u16*)kvbuf;
    float* ksL   = (float*)kvbuf;             // 1200 floats, dead before first kv stage
    int tid = threadIdx.x;
    int n0 = blockIdx.x * AT_NT;              // grid = NN/48 = 625 exact

    for (int i = tid; i < AT_NT * NH * MF; i += 256) {   // qp -> transposed LDS
        int j48 = i / (NH * MF); int r = i - j48 * (NH * MF);
        int h = r / MF; int m = r - h * MF;
        qpTf[j48 >> 4][h * 484 + m * 16 + (j48 & 15)] = qp[(size_t)(n0 + j48) * (NH * MF) + r];
    }
    for (int i = tid; i < NH * KG * MF; i += 256) ksL[i] = ksum[i];
    __syncthreads();
    for (int i = tid; i < AT_NT * NH * KG; i += 256) {   // rden = 1/(qp.ksum)
        int j48 = i / (NH * KG); int r = i - j48 * (NH * KG);
        int h = r / KG;
        int sub = j48 >> 4, j = j48 & 15;
        float s = 0.f;
        #pragma unroll
        for (int m = 0; m < MF; ++m) s += qpTf[sub][h * 484 + m * 16 + j] * ksL[r * MF + m];
        rdenL[sub][j * (NH * KG) + r] = 1.0f / s;
    }

    const int h  = tid >> 6;
    const int jg = (tid >> 4) & 3;
    const int dg = tid & 15;
    float acc[3][4][4] = {};
    for (int k = 0; k < KG; ++k) {
        __syncthreads();   // also protects ksL->kvL16 overlay on first iteration
        for (int i = tid; i < NH * MF * DH; i += 256) {  // stage kvs[:,k,:,:] as bf16
            int hh = i / (MF * DH); int r = i - hh * (MF * DH);
            kvL16[hh * 1928 + r] = f2bf(kvs[((size_t)(hh * KG + k) * MF) * DH + r]);
        }
        __syncthreads();
        float ps[3][4][4] = {};
        const u16* kb = kvL16 + h * 1928 + dg * 4;
        const float* qb0 = qpTf[0] + h * 484 + jg * 4;
        const float* qb1 = qpTf[1] + h * 484 + jg * 4;
        const float* qb2 = qpTf[2] + h * 484 + jg * 4;
        #pragma unroll
        for (int m = 0; m < MF; ++m) {
            ushort4 bu = *(const ushort4*)(kb + m * 64);
            float4 b = make_float4(u2f(bu.x), u2f(bu.y), u2f(bu.z), u2f(bu.w));
            float4 a0 = *(const float4*)(qb0 + m * 16);
            float4 a1 = *(const float4*)(qb1 + m * 16);
            float4 a2 = *(const float4*)(qb2 + m * 16);
            ps[0][0][0] += a0.x * b.x; ps[0][0][1] += a0.x * b.y; ps[0][0][2] += a0.x * b.z; ps[0][0][3] += a0.x * b.w;
            ps[0][1][0] += a0.y * b.x; ps[0][1][1] += a0.y * b.y; ps[0][1][2] += a0.y * b.z; ps[0][1][3] += a0.y * b.w;
            ps[0][2][0] += a0.z * b.x; ps[0][2][1] += a0.z * b.y; ps[0][2][2] += a0.z * b.z; ps[0][2][3] += a0.z * b.w;
            ps[0][3][0] += a0.w * b.x; ps[0][3][1] += a0.w * b.y; ps[0][3][2] += a0.w * b.z; ps[0][3][3] += a0.w * b.w;
            ps[1][0][0] += a1.x * b.x; ps[1][0][1] += a1.x * b.y; ps[1][0][2] += a1.x * b.z; ps[1][0][3] += a1.x * b.w;
            ps[1][1][0] += a1.y * b.x; ps[1][1][1] += a1.y * b.y; ps[1][1][2] += a1.y * b.z; ps[1][1][3] += a1.y * b.w;
            ps[1][2][0] += a1.z * b.x; ps[1][2][1] += a1.z * b.y; ps[1][2][2] += a1.z * b.z; ps[1][2][3] += a1.z * b.w;
            ps[1][3][0] += a1.w * b.x; ps[1][3][1] += a1.w * b.y; ps[1][3][2] += a1.w * b.z; ps[1][3][3] += a1.w * b.w;
            ps[2][0][0] += a2.x * b.x; ps[2][0][1] += a2.x * b.y; ps[2][0][2] += a2.x * b.z; ps[2][0][3] += a2.x * b.w;
            ps[2][1][0] += a2.y * b.x; ps[2][1][1] += a2.y * b.y; ps[2][1][2] += a2.y * b.z; ps[2][1][3] += a2.y * b.w;
            ps[2][2][0] += a2.z * b.x; ps[2][2][1] += a2.z * b.y; ps[2][2][2] += a2.z * b.z; ps[2][2][3] += a2.z * b.w;
            ps[2][3][0] += a2.w * b.x; ps[2][3][1] += a2.w * b.y; ps[2][3][2] += a2.w * b.z; ps[2][3][3] += a2.w * b.w;
        }
        #pragma unroll
        for (int sub = 0; sub < 3; ++sub)
            #pragma unroll
            for (int j4 = 0; j4 < 4; ++j4) {
                float rd = rdenL[sub][(jg * 4 + j4) * (NH * KG) + h * KG + k];
                #pragma unroll
                for (int d4 = 0; d4 < 4; ++d4) acc[sub][j4][d4] += ps[sub][j4][d4] * rd;
            }
    }
    #pragma unroll
    for (int sub = 0; sub < 3; ++sub)
        #pragma unroll
        for (int j4 = 0; j4 < 4; ++j4) {
            int n = n0 + sub * 16 + jg * 4 + j4;
            #pragma unroll
            for (int d4 = 0; d4 < 4; ++d4)
                zatt[(size_t)n * 256 + h * 64 + dg * 4 + d4] = f2bf(acc[sub][j4][d4] * (1.0f / KG));
        }
}

// ---------------- conv gather: wave-per-node, zero barriers ----------------
// Round 16: block-per-node k_conv was latency-bound at 260-295us (VALUBusy 14%,
// hbm 5%) -- per-block serial chain (2x2 barriers + per-node 64KB Wo matvec
// re-read) dominated. Now: each WAVE owns one node (dn wave-uniform -> __shfl
// broadcast of csr/wedge is divergence-safe, unlike round-14's half-split).
// 8-deep unrolled row loads (uint2/lane x 64 lanes = full 512B row per issue)
// -> 8 rows in flight/wave, 32/block. No LDS, no syncs. Output: pre[n,256] =
// zatt + sigb*conv as bf16 (one extra bf16 round vs fp32 path; est +0.005
// absmax vs 0.0129 threshold). Wo projection moves to k_out (MFMA).
__global__ __launch_bounds__(256) void k_gather(
    const u16* __restrict__ zatt, const u16* __restrict__ V16,
    const int* __restrict__ csr, const float* __restrict__ wedge,
    const int* __restrict__ offn, const int* __restrict__ din,
    const float* __restrict__ params, u16* __restrict__ pre)
{
    int tid = threadIdx.x;
    int w = tid >> 6, l = tid & 63;
    int n = blockIdx.x * 4 + w;             // grid = NN/4 = 7500 exact
    float sigb = 1.f / (1.f + expf(-params[P_BBF + (l >> 4)]));   // head of elems l*4..l*4+3
    int dn = din[n], o0 = offn[n];
    float c0 = 0.f, c1 = 0.f, c2 = 0.f, c3 = 0.f;
    for (int t0 = 0; t0 < dn; t0 += 64) {
        int cnt = min(64, dn - t0);
        int myIdx = 0; float myW = 0.f;
        if (l < cnt) { myIdx = csr[o0 + t0 + l]; myW = wedge[o0 + t0 + l]; }
        int j = 0;
        for (; j + 7 < cnt; j += 8) {       // 8 rows in flight (wave-uniform trip count)
            int   s0 = __shfl(myIdx, j),     s1 = __shfl(myIdx, j + 1);
            int   s2 = __shfl(myIdx, j + 2), s3 = __shfl(myIdx, j + 3);
            int   s4 = __shfl(myIdx, j + 4), s5 = __shfl(myIdx, j + 5);
            int   s6 = __shfl(myIdx, j + 6), s7 = __shfl(myIdx, j + 7);
            float w0 = __shfl(myW, j),     w1 = __shfl(myW, j + 1);
            float w2 = __shfl(myW, j + 2), w3 = __shfl(myW, j + 3);
            float w4 = __shfl(myW, j + 4), w5 = __shfl(myW, j + 5);
            float w6 = __shfl(myW, j + 6), w7 = __shfl(myW, j + 7);
            uint2 a0 = *(const uint2*)(V16 + (size_t)s0 * 256 + l * 4);
            uint2 a1 = *(const uint2*)(V16 + (size_t)s1 * 256 + l * 4);
            uint2 a2 = *(const uint2*)(V16 + (size_t)s2 * 256 + l * 4);
            uint2 a3 = *(const uint2*)(V16 + (size_t)s3 * 256 + l * 4);
            uint2 a4 = *(const uint2*)(V16 + (size_t)s4 * 256 + l * 4);
            uint2 a5 = *(const uint2*)(V16 + (size_t)s5 * 256 + l * 4);
            uint2 a6 = *(const uint2*)(V16 + (size_t)s6 * 256 + l * 4);
            uint2 a7 = *(const uint2*)(V16 + (size_t)s7 * 256 + l * 4);
            c0 += w0 * u2f((u16)(a0.x & 0xFFFF)) + w1 * u2f((u16)(a1.x & 0xFFFF))
                + w2 * u2f((u16)(a2.x & 0xFFFF)) + w3 * u2f((u16)(a3.x & 0xFFFF))
                + w4 * u2f((u16)(a4.x & 0xFFFF)) + w5 * u2f((u16)(a5.x & 0xFFFF))
                + w6 * u2f((u16)(a6.x & 0xFFFF)) + w7 * u2f((u16)(a7.x & 0xFFFF));
            c1 += w0 * u2f((u16)(a0.x >> 16)) + w1 * u2f((u16)(a1.x >> 16))
                + w2 * u2f((u16)(a2.x >> 16)) + w3 * u2f((u16)(a3.x >> 16))
                + w4 * u2f((u16)(a4.x >> 16)) + w5 * u2f((u16)(a5.x >> 16))
                + w6 * u2f((u16)(a6.x >> 16)) + w7 * u2f((u16)(a7.x >> 16));
            c2 += w0 * u2f((u16)(a0.y & 0xFFFF)) + w1 * u2f((u16)(a1.y & 0xFFFF))
                + w2 * u2f((u16)(a2.y & 0xFFFF)) + w3 * u2f((u16)(a3.y & 0xFFFF))
                + w4 * u2f((u16)(a4.y & 0xFFFF)) + w5 * u2f((u16)(a5.y & 0xFFFF))
                + w6 * u2f((u16)(a6.y & 0xFFFF)) + w7 * u2f((u16)(a7.y & 0xFFFF));
            c3 += w0 * u2f((u16)(a0.y >> 16)) + w1 * u2f((u16)(a1.y >> 16))
                + w2 * u2f((u16)(a2.y >> 16)) + w3 * u2f((u16)(a3.y >> 16))
                + w4 * u2f((u16)(a4.y >> 16)) + w5 * u2f((u16)(a5.y >> 16))
                + w6 * u2f((u16)(a6.y >> 16)) + w7 * u2f((u16)(a7.y >> 16));
        }
        for (; j < cnt; ++j) {
            int   s0 = __shfl(myIdx, j);
            float w0 = __shfl(myW, j);
            uint2 a0 = *(const uint2*)(V16 + (size_t)s0 * 256 + l * 4);
            c0 += w0 * u2f((u16)(a0.x & 0xFFFF));
            c1 += w0 * u2f((u16)(a0.x >> 16));
            c2 += w0 * u2f((u16)(a0.y & 0xFFFF));
            c3 += w0 * u2f((u16)(a0.y >> 16));
        }
    }
    uint2 za = *(const uint2*)(zatt + (size_t)n * 256 + l * 4);
    float e0 = u2f((u16)(za.x & 0xFFFF)) + sigb * c0;
    float e1 = u2f((u16)(za.x >> 16))    + sigb * c1;
    float e2 = u2f((u16)(za.y & 0xFFFF)) + sigb * c2;
    float e3 = u2f((u16)(za.y >> 16))    + sigb * c3;
    uint2 r;
    r.x = (u32)f2bf(e0) | ((u32)f2bf(e1) << 16);
    r.y = (u32)f2bf(e2) | ((u32)f2bf(e3) << 16);
    *(uint2*)(pre + (size_t)n * 256 + l * 4) = r;
}

// ---------------- out = pre(bf16) x Wo^T via MFMA (Wo hi/lo split on the fly) ----------------
// 64-row tiles, grid 469. Wo (64KB fp32) read 469x instead of 30000x.
__global__ __launch_bounds__(256) void k_out(
    const u16* __restrict__ pre, const float* __restrict__ params, float* __restrict__ out)
{
    __shared__ __align__(16) char smemc[24576];   // As(8KB) | BsH(8KB) | BsL(8KB)
    char* As  = smemc;
    char* BsH = smemc + 8192;
    char* BsL = smemc + 16384;
    const int tid = threadIdx.x;
    const int bm = blockIdx.x * 64;
    const int wave = tid >> 6, lane = tid & 63;
    const int wm = wave >> 1, wn = wave & 1;
    const int sr = tid >> 2;
    const int sc = (tid & 3) * 16;

    f32x4 acc[2][2] = {};

    for (int k0 = 0; k0 < 256; k0 += 64) {
        __syncthreads();
        int byt0 = sr * 128 + (((sc + 0) * 2) ^ ((sr & 7) << 4));
        int byt1 = sr * 128 + (((sc + 8) * 2) ^ ((sr & 7) << 4));
        {   // ---- stage A: pre rows (bf16 copy) ----
            int row = bm + sr;
            uint4 v0 = make_uint4(0, 0, 0, 0), v1 = v0;
            if (row < NN) {
                const uint4* p = (const uint4*)(pre + (size_t)row * 256 + k0 + sc);
                v0 = p[0]; v1 = p[1];
            }
            *(uint4*)(As + byt0) = v0;
            *(uint4*)(As + byt1) = v1;
        }
        {   // ---- stage B: Wo fp32 -> hi/lo bf16 planes ----
            float x[16];
            const float4* wr = (const float4*)(params + P_WOF + (size_t)sr * 256 + k0 + sc);
            #pragma unroll
            for (int q4 = 0; q4 < 4; ++q4) {
                float4 v = wr[q4];
                x[q4 * 4 + 0] = v.x; x[q4 * 4 + 1] = v.y;
                x[q4 * 4 + 2] = v.z; x[q4 * 4 + 3] = v.w;
            }
            #pragma unroll
            for (int j8 = 0; j8 < 2; ++j8) {
                u32 hw[4], lw[4];
                #pragma unroll
                for (int p = 0; p < 4; ++p) {
                    float a = x[j8 * 8 + 2 * p], b2 = x[j8 * 8 + 2 * p + 1];
                    u16 ha = f2bf(a), hb = f2bf(b2);
                    hw[p] = (u32)ha | ((u32)hb << 16);
                    u16 la = f2bf(a - u2f(ha)), lb = f2bf(b2 - u2f(hb));
                    lw[p] = (u32)la | ((u32)lb << 16);
                }
                int byt = sr * 128 + (((sc + j8 * 8) * 2) ^ ((sr & 7) << 4));
                *(uint4*)(BsH + byt) = make_uint4(hw[0], hw[1], hw[2], hw[3]);
                *(uint4*)(BsL + byt) = make_uint4(lw[0], lw[1], lw[2], lw[3]);
            }
        }
        __syncthreads();
        #pragma unroll
        for (int kk = 0; kk < 2; ++kk) {
            const int kb = (kk * 32 + ((lane >> 4) * 8)) * 2;
            bf16x8 a[2], bh[2], bl[2];
            #pragma unroll
            for (int i = 0; i < 2; ++i) {
                int ar = 32 * wm + 16 * i + (lane & 15);
                int ab = ar * 128 + (kb ^ ((ar & 7) << 4));
                a[i] = *(const bf16x8*)(As + ab);
                int br = 32 * wn + 16 * i + (lane & 15);
                int bb2 = br * 128 + (kb ^ ((br & 7) << 4));
                bh[i] = *(const bf16x8*)(BsH + bb2);
                bl[i] = *(const bf16x8*)(BsL + bb2);
            }
            #pragma unroll
            for (int i = 0; i < 2; ++i)
                #pragma unroll
                for (int nf = 0; nf < 2; ++nf) {
                    acc[i][nf] = __builtin_amdgcn_mfma_f32_16x16x32_bf16(a[i], bh[nf], acc[i][nf], 0, 0, 0);
                    acc[i][nf] = __builtin_amdgcn_mfma_f32_16x16x32_bf16(a[i], bl[nf], acc[i][nf], 0, 0, 0);
                }
        }
    }
    #pragma unroll
    for (int i = 0; i < 2; ++i)
        #pragma unroll
        for (int nf = 0; nf < 2; ++nf) {
            int col = 32 * wn + 16 * nf + (lane & 15);
            float bias = params[P_WOBF + col];
            #pragma unroll
            for (int r2 = 0; r2 < 4; ++r2) {
                int row = bm + 32 * wm + 16 * i + ((lane >> 4) * 4) + r2;
                if (row < NN) out[(size_t)row * 64 + col] = acc[i][nf][r2] + bias;
            }
        }
}

// ---------------- loss finalize ----------------
__global__ __launch_bounds__(256) void k_loss(const float* __restrict__ lossp, float* __restrict__ out) {
    __shared__ float s[256];
    int tid = threadIdx.x;
    float v = 0.f;
    for (int i = tid; i < 1024; i += 256) v += lossp[i];
    s[tid] = v;
    __syncthreads();
    for (int o = 128; o > 0; o >>= 1) {
        if (tid < o) s[tid] += s[tid + o];
        __syncthreads();
    }
    if (tid == 0) out[(size_t)NN * 64] = s[0] / (float)(NE * NH);   // fp32 output
}

extern "C" void kernel_launch(void* const* d_in, const int* in_sizes, int n_in,
                              void* d_out, int out_size, void* d_ws, size_t ws_size,
                              hipStream_t stream)
{
    const void* z    = d_in[0];
    const int*  ei   = (const int*)d_in[1];
    const void* taup = d_in[2];
    const void* gum  = d_in[3];
    const void* proj = d_in[4];
    const void* Wq   = d_in[5];
    const void* bq   = d_in[6];
    const void* Wk   = d_in[7];
    const void* bk   = d_in[8];
    const void* Wv   = d_in[9];
    const void* bv   = d_in[10];
    const void* Wo   = d_in[11];
    const void* Wob  = d_in[12];
    const void* bb   = d_in[13];
    float* out = (float*)d_out;

    // ---- workspace carve-up (fp32 units), total ~67 MB ----
    u16*   V16    = (u16*)d_ws;                    //  7,680,000 u16 : [N,256] bf16 V
    float* qpb    = (float*)d_ws + 3840000;        //  3,600,000 : [N,H,M]
    float* kpb    = qpb + (size_t)NN * NH * MF;    //  3,600,000 : dashK then kp in-place
    float* diagK  = kpb + (size_t)NN * NH * MF;    //    120,000
    float* anb    = diagK + (size_t)NN * NH;       //    120,000
    u16*   zatt   = (u16*)kpb;                     //  reuses kpb+diagK+anb (dead after k_edge)
    int*   csr    = (int*)(anb + (size_t)NN * NH); //    480,000
    int*   offn   = csr + NE;                      //     30,000
    float* params = (float*)(offn + NN);           //    215,749 (+pad to 215,752)
    // ---- zeroed accumulator region ----
    float* kvs    = params + 215752;               //     76,800 : [H,K,M,D]
    float* ksum   = kvs + NH * KG * MF * DH;       //      1,200 : [H,K,M]
    float* kpsum  = ksum + NH * KG * MF;           //        120 : [H,M]
    int*   din    = (int*)(kpsum + NH * MF);       //     30,000
    int*   doutd  = din + NN;                      //     30,000
    int*   fill   = doutd + NN;                    //     30,000
    int*   counter = fill + NN;                    //          4
    u32*   stab   = (u32*)(counter + 4);           //          4
    float* lossp  = (float*)(stab + 4);            //      1,024
    int*   flag   = (int*)(lossp + 1024);          //          4
    float* wedge  = (float*)(flag + 4);            //    480,000 (not zeroed; fully written)
    u16*   qp16   = (u16*)(wedge + NE);            //  3,840,000 u16 : [N,H,32] bf16 qp
    u16*   kp16   = qp16 + (size_t)NN * NH * 32;   //  3,840,000 u16 : [N,H,32] bf16 kp
    // kvs partials overlay qp16+kp16 (15.36 MB, exact fit: 50*4*4*4800 floats);
    // alive only between k_kvs and k_reduce, after qp16/kp16's last reader (k_edge).
    float* Pkvs   = (float*)qp16;
    float* Pksum  = (float*)(kp16 + (size_t)NN * NH * 32);   //  60,000 floats (new tail)
    // W hi/lo bf16 planes overlay kp16 (dead until k_kp writes it, after k_gemm_feat)
    u16*   Whb    = kp16;                          //    196,608 u16 : [768][256] W hi
    u16*   Wlb    = kp16 + 196608;                 //    196,608 u16 : [768][256] W lo
    // pre[N,256] bf16 overlays qp16+kp16 (7,680,000 u16 exactly); alive only
    // between k_gather and k_out, after Pkvs's last reader (k_reduce).
    u16*   pre    = qp16;
    size_t zero_bytes = (size_t)((char*)(flag + 4) - (char*)kvs);

    hipMemsetAsync(kvs, 0, zero_bytes, stream);

    k_detect<<<dim3(1), dim3(64), 0, stream>>>((const u16*)z, flag);
    k_cvt_params<<<dim3((P_TOTAL + 255) / 256), dim3(256), 0, stream>>>(
        Wq, Wk, Wv, bq, bk, bv, Wo, Wob, bb, proj, taup, params, flag);
    k_cvt_w<<<dim3(768), dim3(256), 0, stream>>>(params, Whb, Wlb);

    k_deg <<<dim3((NE + 255) / 256), dim3(256), 0, stream>>>(ei, din, doutd);
    k_off <<<dim3((NN + 255) / 256), dim3(256), 0, stream>>>(din, offn, counter);
    k_fill<<<dim3((NE + 255) / 256), dim3(256), 0, stream>>>(ei, offn, fill, csr, din, doutd, wedge);
    k_gemm_feat<<<dim3((NN + 63) / 64, 12), dim3(256), 0, stream>>>(
        z, params, flag, Whb, Wlb, V16, qpb, qp16, kpb, diagK, stab);
    k_kp  <<<dim3(NN * NH / 64), dim3(256), 0, stream>>>(kpb, diagK, stab, kpsum, kp16);
    k_an  <<<dim3((NN * NH + 255) / 256), dim3(256), 0, stream>>>(qpb, kpsum, anb);
    k_edge<<<dim3(NE / 64), dim3(256), 0, stream>>>(ei, qp16, kp16, anb, din, lossp);
    // qp16/kp16 dead from here; Pkvs overlays them (stream-ordered)
    k_kvs <<<dim3(KVS_CHUNKS, NH, DH / KVS_DZ), dim3(320), 0, stream>>>(kpb, gum, V16, flag, Pkvs, Pksum);
    k_reduce<<<dim3((NH * KG * MF * DH + NH * KG * MF + 255) / 256), dim3(256), 0, stream>>>(
        Pkvs, Pksum, kvs, ksum);
    // zatt overwrites kpb/diagK/anb from here on (stream-ordered after their last readers)
    k_attn<<<dim3(NN / AT_NT), dim3(256), 0, stream>>>(qpb, kvs, ksum, zatt);
    // pre overlays qp16/kp16 (Pkvs dead after k_reduce)
    k_gather<<<dim3(NN / 4), dim3(256), 0, stream>>>(zatt, V16, csr, wedge, offn, din, params, pre);
    k_out<<<dim3((NN + 63) / 64), dim3(256), 0, stream>>>(pre, params, out);
    k_loss<<<dim3(1), dim3(256), 0, stream>>>(lossp, out);
}

// Round 6
// 677.411 us; speedup vs baseline: 1.4659x; 1.1254x over previous
//
#include <hip/hip_runtime.h>
#include <hip/hip_bf16.h>

#define NN 30000
#define NE 480000
#define NH 4
#define DH 64
#define MF 30
#define KG 10
#define RATIO 0.18257418583505536f   /* 1/sqrt(30) */
#define DNRM  0.35355339059327373f   /* 64^-0.25  */

// fp32 params block layout (element offsets)
#define P_WF    0        /* [768][256] Wq|Wk|Wv rows */
#define P_BF    196608   /* [768] bq|bk|bv */
#define P_WOF   197376   /* [64][256] Wo */
#define P_WOBF  213760   /* [64] Wo bias */
#define P_BBF   213824   /* [4] rb bias b */
#define P_PROJ  213828   /* [30][64] proj */
#define P_TAU   215748   /* scalar */
#define P_TOTAL 215749

typedef unsigned short u16;
typedef unsigned int   u32;
typedef __attribute__((ext_vector_type(8))) short bf16x8;
typedef __attribute__((ext_vector_type(4))) float f32x4;

__device__ __forceinline__ float u2f(u16 u) { return __uint_as_float(((u32)u) << 16); }
__device__ __forceinline__ u16  f2bf(float f) {  // round-to-nearest-even bf16
    u32 x = __float_as_uint(f);
    return (u16)((x + 0x7FFFu + ((x >> 16) & 1u)) >> 16);
}
// order-preserving float->uint encoding for atomicMax over signed floats
__device__ __forceinline__ u32  encf(float f) { u32 u = __float_as_uint(f); return (u & 0x80000000u) ? ~u : (u | 0x80000000u); }
__device__ __forceinline__ float decf(u32 u)  { return (u & 0x80000000u) ? __uint_as_float(u & 0x7FFFFFFFu) : __uint_as_float(~u); }

// ---------------- dtype detection (fp32 vs bf16 input tensors) ----------------
__global__ void k_detect(const u16* __restrict__ z, int* __restrict__ flag) {
    if (threadIdx.x == 0 && blockIdx.x == 0) {
        int bad = 0;
        for (int i = 0; i < 256; i += 2) {
            u16 u = z[i];
            int e = (u >> 7) & 0xFF;
            if (u != 0 && !(e >= 100 && e <= 140)) bad++;
        }
        *flag = (bad > 16) ? 1 : 0;   // 1 = inputs are fp32
    }
}

// ---------------- stage all small params to fp32 ----------------
__global__ __launch_bounds__(256) void k_cvt_params(
    const void* Wq, const void* Wk, const void* Wv,
    const void* bq, const void* bk, const void* bv,
    const void* Wo, const void* Wob, const void* bb, const void* proj,
    const void* taup, float* __restrict__ params, const int* __restrict__ flag)
{
    int i = blockIdx.x * 256 + threadIdx.x;
    if (i >= P_TOTAL) return;
    int f = *flag;
    if (i == P_TAU) {
        float v = f ? ((const float*)taup)[0] : u2f(((const u16*)taup)[0]);
        if (!(v > 1e-6f && v < 1e6f)) {
            float ff = ((const float*)taup)[0];
            v = (ff > 1e-6f && ff < 1e6f) ? ff : 0.25f;
        }
        params[i] = v;
        return;
    }
    const void* src; int j;
    if      (i < 65536)  { src = Wq;  j = i; }
    else if (i < 131072) { src = Wk;  j = i - 65536; }
    else if (i < 196608) { src = Wv;  j = i - 131072; }
    else if (i < 196864) { src = bq;  j = i - 196608; }
    else if (i < 197120) { src = bk;  j = i - 196864; }
    else if (i < 197376) { src = bv;  j = i - 197120; }
    else if (i < 213760) { src = Wo;  j = i - 197376; }
    else if (i < 213824) { src = Wob; j = i - 213760; }
    else if (i < 213828) { src = bb;  j = i - 213824; }
    else                 { src = proj; j = i - P_PROJ; }
    params[i] = f ? ((const float*)src)[j] : u2f(((const u16*)src)[j]);
}

// ---------------- hi/lo bf16 split of W (once; gemm staging becomes pure copy) ----------------
__global__ __launch_bounds__(256) void k_cvt_w(const float* __restrict__ params,
                                               u16* __restrict__ Wh, u16* __restrict__ Wl)
{
    int i = blockIdx.x * 256 + threadIdx.x;   // grid = 768 blocks, 196608 exact
    float x = params[P_WF + i];
    u16 h = f2bf(x);
    Wh[i] = h;
    Wl[i] = f2bf(x - u2f(h));
}

// ---------------- degrees ----------------
__global__ __launch_bounds__(256) void k_deg(const int* __restrict__ ei, int* __restrict__ din, int* __restrict__ dout) {
    int e = blockIdx.x * 256 + threadIdx.x;
    if (e >= NE) return;
    atomicAdd(&dout[ei[e]], 1);
    atomicAdd(&din[ei[NE + e]], 1);
}

// ---------------- scan-free CSR offsets ----------------
__global__ __launch_bounds__(256) void k_off(const int* __restrict__ din, int* __restrict__ offn, int* __restrict__ counter) {
    __shared__ int s[256];
    __shared__ int base;
    int tid = threadIdx.x;
    int n = blockIdx.x * 256 + tid;
    int v = (n < NN) ? din[n] : 0;
    s[tid] = v;
    __syncthreads();
    for (int o = 1; o < 256; o <<= 1) {
        int t = (tid >= o) ? s[tid - o] : 0;
        __syncthreads();
        s[tid] += t;
        __syncthreads();
    }
    if (tid == 255) base = atomicAdd(counter, s[255]);
    __syncthreads();
    if (n < NN) offn[n] = base + s[tid] - v;
}

// fill CSR + precompute per-edge conv weight w = rsqrt(din[t]*dout[s])
__global__ __launch_bounds__(256) void k_fill(const int* __restrict__ ei, const int* __restrict__ offn,
                                              int* __restrict__ fill, int* __restrict__ csr,
                                              const int* __restrict__ din, const int* __restrict__ dout,
                                              float* __restrict__ wedge) {
    int e = blockIdx.x * 256 + threadIdx.x;
    if (e >= NE) return;
    int s = ei[e], t = ei[NE + e];
    int pos = offn[t] + atomicAdd(&fill[t], 1);
    csr[pos] = s;
    wedge[pos] = rsqrtf((float)din[t] * (float)dout[s]);
}

// ---------------- fused QKV GEMM (bf16 MFMA, hi/lo split) + Performer epilogue ----------------
// grid (ceil(NN/64), 12): y 0..3 -> Q head y; y 4..7 -> K head y-4; y 8..11 -> V cols.
// fp32 inputs: A,B split into hi+lo bf16 planes; C = Ah*Bh + Ah*Bl + Al*Bh (3 MFMA passes,
// rel err ~2^-17 -- below the bf16 noise already accepted downstream). bf16 inputs: 1 exact pass.
// LDS planes are 128B-row tiles with T2 XOR swizzle (byte ^= (row&7)<<4) on write AND read.
__global__ __launch_bounds__(256) void k_gemm_feat(
    const void* __restrict__ zv, const float* __restrict__ params, const int* __restrict__ flag,
    const u16* __restrict__ Wh, const u16* __restrict__ Wl,
    u16* __restrict__ V16, float* __restrict__ qp, u16* __restrict__ qp16,
    float* __restrict__ dashK, float* __restrict__ diagK, u32* __restrict__ stab)
{
    __shared__ __align__(16) char smemc[32768];  // 4 bf16 planes of 64x64 (8 KB each)
    __shared__ u32 smaxL;
    char* AsH = smemc;                // A hi plane
    char* AsL = smemc + 8192;         // A lo plane
    char* BsH = smemc + 16384;        // B hi plane
    char* BsL = smemc + 24576;        // B lo plane
    float* tile  = (float*)smemc;          // 64 x 68 fp32 epilogue tile (overlays planes)
    float* projL = (float*)smemc + 4352;   // 30 x 65 (overlays planes; staged after GEMM)

    const int tid = threadIdx.x;
    const int bm = blockIdx.x * 64;
    const int bn = blockIdx.y * 64;
    const int f32 = *flag;
    const int wave = tid >> 6, lane = tid & 63;
    const int wm = wave >> 1, wn = wave & 1;     // 2x2 wave grid, each wave 32x32
    const int sr = tid >> 2;                     // staging row 0..63
    const int sc = (tid & 3) * 16;               // staging col base (16 cols/thread/chunk)

    f32x4 acc[2][2] = {};

    for (int k0 = 0; k0 < 256; k0 += 64) {
        __syncthreads();
        // ---------- stage A (z), hi/lo split on the fly ----------
        {
            int zrow = bm + sr;
            if (f32) {
                float x[16];
                if (zrow < NN) {
                    const float4* zp = (const float4*)((const float*)zv + (size_t)zrow * 256 + k0 + sc);
                    #pragma unroll
                    for (int q4 = 0; q4 < 4; ++q4) {
                        float4 v = zp[q4];
                        x[q4 * 4 + 0] = v.x; x[q4 * 4 + 1] = v.y;
                        x[q4 * 4 + 2] = v.z; x[q4 * 4 + 3] = v.w;
                    }
                } else {
                    #pragma unroll
                    for (int j = 0; j < 16; ++j) x[j] = 0.f;
                }
                #pragma unroll
                for (int j8 = 0; j8 < 2; ++j8) {
                    u32 hw[4], lw[4];
                    #pragma unroll
                    for (int p = 0; p < 4; ++p) {
                        float a = x[j8 * 8 + 2 * p], b2 = x[j8 * 8 + 2 * p + 1];
                        u16 ha = f2bf(a), hb = f2bf(b2);
                        hw[p] = (u32)ha | ((u32)hb << 16);
                        u16 la = f2bf(a - u2f(ha)), lb = f2bf(b2 - u2f(hb));
                        lw[p] = (u32)la | ((u32)lb << 16);
                    }
                    int byt = sr * 128 + (((sc + j8 * 8) * 2) ^ ((sr & 7) << 4));
                    *(uint4*)(AsH + byt) = make_uint4(hw[0], hw[1], hw[2], hw[3]);
                    *(uint4*)(AsL + byt) = make_uint4(lw[0], lw[1], lw[2], lw[3]);
                }
            } else {
                uint4 v0 = make_uint4(0, 0, 0, 0), v1 = v0;
                if (zrow < NN) {
                    const uint4* zp = (const uint4*)((const u16*)zv + (size_t)zrow * 256 + k0 + sc);
                    v0 = zp[0]; v1 = zp[1];
                }
                int byt0 = sr * 128 + (((sc + 0) * 2) ^ ((sr & 7) << 4));
                int byt1 = sr * 128 + (((sc + 8) * 2) ^ ((sr & 7) << 4));
                *(uint4*)(AsH + byt0) = v0;
                *(uint4*)(AsH + byt1) = v1;
            }
        }
        // ---------- stage B (preconverted W hi/lo: pure copy) ----------
        {
            int byt0 = sr * 128 + (((sc + 0) * 2) ^ ((sr & 7) << 4));
            int byt1 = sr * 128 + (((sc + 8) * 2) ^ ((sr & 7) << 4));
            const uint4* wh4 = (const uint4*)(Wh + (size_t)(bn + sr) * 256 + k0 + sc);
            *(uint4*)(BsH + byt0) = wh4[0];
            *(uint4*)(BsH + byt1) = wh4[1];
            if (f32) {
                const uint4* wl4 = (const uint4*)(Wl + (size_t)(bn + sr) * 256 + k0 + sc);
                *(uint4*)(BsL + byt0) = wl4[0];
                *(uint4*)(BsL + byt1) = wl4[1];
            }
        }
        __syncthreads();
        // ---------- MFMA: 2 k-steps of 32 per chunk ----------
        #pragma unroll
        for (int kk = 0; kk < 2; ++kk) {
            const int kb = (kk * 32 + ((lane >> 4) * 8)) * 2;   // byte col of this lane's 8 k-elems
            bf16x8 ah[2], bh[2], al[2], bl[2];
            #pragma unroll
            for (int i = 0; i < 2; ++i) {
                int ar = 32 * wm + 16 * i + (lane & 15);
                int ab = ar * 128 + (kb ^ ((ar & 7) << 4));
                ah[i] = *(const bf16x8*)(AsH + ab);
                int br = 32 * wn + 16 * i + (lane & 15);
                int bb2 = br * 128 + (kb ^ ((br & 7) << 4));
                bh[i] = *(const bf16x8*)(BsH + bb2);
                if (f32) {
                    al[i] = *(const bf16x8*)(AsL + ab);
                    bl[i] = *(const bf16x8*)(BsL + bb2);
                }
            }
            #pragma unroll
            for (int i = 0; i < 2; ++i)
                #pragma unroll
                for (int nf = 0; nf < 2; ++nf) {
                    acc[i][nf] = __builtin_amdgcn_mfma_f32_16x16x32_bf16(ah[i], bh[nf], acc[i][nf], 0, 0, 0);
                    if (f32) {
                        acc[i][nf] = __builtin_amdgcn_mfma_f32_16x16x32_bf16(ah[i], bl[nf], acc[i][nf], 0, 0, 0);
                        acc[i][nf] = __builtin_amdgcn_mfma_f32_16x16x32_bf16(al[i], bh[nf], acc[i][nf], 0, 0, 0);
                    }
                }
        }
    }
    __syncthreads();   // all plane reads done; smem reusable as tile/projL

    const float* bfv = params + P_BF;
    if (bn >= 512) {   // ---- V: acc -> tile (+bias) -> coalesced bf16 store ----
        #pragma unroll
        for (int i = 0; i < 2; ++i)
            #pragma unroll
            for (int nf = 0; nf < 2; ++nf) {
                int col = 32 * wn + 16 * nf + (lane & 15);
                float bias = bfv[bn + col];
                #pragma unroll
                for (int r2 = 0; r2 < 4; ++r2) {
                    int row = 32 * wm + 16 * i + ((lane >> 4) * 4) + r2;
                    tile[row * 68 + col] = acc[i][nf][r2] + bias;
                }
            }
        __syncthreads();
        for (int i2 = tid; i2 < 4096; i2 += 256) {
            int row = i2 >> 6, col = i2 & 63;
            int nrow = bm + row;
            if (nrow < NN) V16[(size_t)nrow * 256 + (bn - 512) + col] = f2bf(tile[row * 68 + col]);
        }
        return;
    }

    // ---- Q/K: performer features on the 64x64 head tile ----
    for (int i2 = tid; i2 < MF * DH; i2 += 256) projL[(i2 >> 6) * 65 + (i2 & 63)] = params[P_PROJ + i2];
    if (tid == 0) smaxL = 0u;
    float scale = DNRM * rsqrtf(params[P_TAU]);
    #pragma unroll
    for (int i = 0; i < 2; ++i)
        #pragma unroll
        for (int nf = 0; nf < 2; ++nf) {
            int col = 32 * wn + 16 * nf + (lane & 15);
            float bias = bfv[bn + col];
            #pragma unroll
            for (int r2 = 0; r2 < 4; ++r2) {
                int row = 32 * wm + 16 * i + ((lane >> 4) * 4) + r2;
                tile[row * 68 + col] = (acc[i][nf][r2] + bias) * scale;
            }
        }
    __syncthreads();

    int r = tid >> 2, q = tid & 3;      // 4 lanes cooperate per row; same wave
    int n = bm + r;
    const float* trow = tile + r * 68;
    float dp = 0.f;
    #pragma unroll
    for (int d = q * 16; d < q * 16 + 16; ++d) dp += trow[d] * trow[d];
    dp += __shfl_xor(dp, 1);
    dp += __shfl_xor(dp, 2);
    float diag = dp * 0.5f;

    float dm[8];
    int nm = 0;
    float lmax = -3.0e38f;
    for (int m = q; m < MF; m += 4) {
        float s = 0.f;
        #pragma unroll
        for (int d = 0; d < DH; ++d) s += trow[d] * projL[m * 65 + d];
        dm[nm++] = s;
        lmax = fmaxf(lmax, s);
    }
    float mx = fmaxf(lmax, __shfl_xor(lmax, 1));
    mx = fmaxf(mx, __shfl_xor(mx, 2));

    if (bn < 256) {   // Q: row-local stab, write qp (fp32) + packed bf16 copy
        int h = blockIdx.y;
        if (n < NN) {
            float* o = qp + ((size_t)n * NH + h) * MF;
            u16* o16 = qp16 + ((size_t)n * NH + h) * 32;
            nm = 0;
            for (int m = q; m < MF; m += 4) {
                float v = RATIO * (expf(dm[nm++] - diag - mx) + 1e-6f);
                o[m] = v;
                o16[m] = f2bf(v);
            }
            if (q == 0) { o16[30] = 0; o16[31] = 0; }
        }
    } else {          // K: store dash/diag, global per-head max
        int h = blockIdx.y - 4;
        if (n < NN) {
            float* o = dashK + ((size_t)n * NH + h) * MF;
            nm = 0;
            for (int m = q; m < MF; m += 4) o[m] = dm[nm++];
            if (q == 0) {
                diagK[(size_t)n * NH + h] = diag;
                atomicMax(&smaxL, encf(mx));
            }
        }
        __syncthreads();
        if (tid == 0) atomicMax(&stab[h], smaxL);
    }
}

// ---------------- keys pass 2: kp in-place + kpsum + packed bf16 copy ----------------
__global__ __launch_bounds__(256) void k_kp(float* __restrict__ kp, const float* __restrict__ diagK,
                                            const u32* __restrict__ stab, float* __restrict__ kpsum,
                                            u16* __restrict__ kp16)
{
    __shared__ float part[NH * MF];
    __shared__ float stabf[4];
    int tid = threadIdx.x;
    if (tid < NH * MF) part[tid] = 0.f;
    if (tid >= 128 && tid < 132) stabf[tid - 128] = decf(stab[tid - 128]);
    __syncthreads();
    int base = blockIdx.x * 64 * MF;   // 64 rows/block, exact: 1875*64 = 120000
    for (int i = tid; i < 64 * MF; i += 256) {
        int row = blockIdx.x * 64 + i / MF;
        int m = i - (i / MF) * MF;
        int h = row & 3;
        float v = RATIO * (expf(kp[base + i] - diagK[row] - stabf[h]) + 1e-6f);
        kp[base + i] = v;
        kp16[(size_t)row * 32 + m] = f2bf(v);
        atomicAdd(&part[h * MF + m], v);
    }
    if (tid < 64) {
        int row = blockIdx.x * 64 + tid;
        kp16[(size_t)row * 32 + 30] = 0;
        kp16[(size_t)row * 32 + 31] = 0;
    }
    __syncthreads();
    if (tid < NH * MF) atomicAdd(&kpsum[tid], part[tid]);
}

// ---------------- attn_norm[n,h] = qp[n,h,:] . kpsum[h,:] ----------------
__global__ __launch_bounds__(256) void k_an(const float* __restrict__ qp, const float* __restrict__ kpsum,
                                            float* __restrict__ an)
{
    __shared__ float kps[NH * MF];
    int tid = threadIdx.x;
    if (tid < NH * MF) kps[tid] = kpsum[tid];
    __syncthreads();
    int idx = blockIdx.x * 256 + tid;
    if (idx >= NN * NH) return;
    int h = idx & 3;
    const float* q = qp + (size_t)idx * MF;
    float s = 0.f;
    #pragma unroll
    for (int m = 0; m < MF; ++m) s += q[m] * kps[h * MF + m];
    an[idx] = s;
}

// ---------------- kvs via MFMA: kvs[h, km, d] = sum_n kg[n,km] * V[n,h,d] ----------------
// Round 17: old VALU k_kvs was 160us at 40% occupancy, MfmaUtil 0 (broadcast
// LDS reads feeding 16 lane-FMAs each; VALU floor alone ~30us). This is a
// 300x64 GEMM with K=30000 per head -> MFMA. Per block (chunk, head): per
// 64-node tile, build kgT[320][64] bf16 (kg = kp*exp(g), rows>=300 and pad
// nodes zeroed) + VT[64][64] bf16 transpose, XOR-swizzled; 8 waves x 10
// C-tiles x 2 MFMA. ksum accumulated from the SAME bf16-rounded kg values so
// numerator/denominator stay consistent. Pkvs: [chunk][h][300][64] fp32
// partials (3.84M floats = same 15.36MB overlay as before).
#define KVS_CHUNKS 50
#define KVS_NPB (NN / KVS_CHUNKS)    /* 600 nodes per block */
__global__ __launch_bounds__(512) void k_kvs(const float* __restrict__ kp, const void* __restrict__ gum,
                                             const u16* __restrict__ V16, const int* __restrict__ flag,
                                             float* __restrict__ Pkvs, float* __restrict__ Pksum)
{
    __shared__ __align__(16) char kgT[320 * 128];   // 40KB bf16 [320 km][64 n] swizzled
    __shared__ __align__(16) char VT[64 * 128];     //  8KB bf16 [64 d][64 n] swizzled
    __shared__ float kpT[64][31];                    // +1 pad
    __shared__ float egT[64][10];
    const int tid = threadIdx.x;
    const int h = blockIdx.y;
    const int chunk = blockIdx.x;
    const int n0 = chunk * KVS_NPB;
    const int f32 = *flag;
    const int wave = tid >> 6, lane = tid & 63;

    float ksacc[5] = {0.f, 0.f, 0.f, 0.f, 0.f};
    f32x4 acc[10] = {};

    for (int t0 = 0; t0 < KVS_NPB; t0 += 64) {
        __syncthreads();   // prev-tile MFMA reads done
        // ---- stage kp tile (zero-pad past chunk end) ----
        for (int i = tid; i < 64 * MF; i += 512) {
            int n = i / MF, m = i - (i / MF) * MF;
            kpT[n][m] = (t0 + n < KVS_NPB) ? kp[(size_t)(n0 + t0 + n) * (NH * MF) + h * MF + m] : 0.f;
        }
        // ---- stage exp(gumbel) tile ----
        for (int i = tid; i < 64 * KG; i += 512) {
            int n = i / KG, k = i - (i / KG) * KG;
            float e = 0.f;
            if (t0 + n < KVS_NPB) {
                size_t gofs = (size_t)(n0 + t0 + n) * (NH * KG) + h * KG + k;
                float g = f32 ? ((const float*)gum)[gofs] : u2f(((const u16*)gum)[gofs]);
                e = expf(g);
            }
            egT[n][k] = e;
        }
        // ---- stage V^T tile (u16 scatter, swizzled) ----
        for (int i = tid; i < 64 * 16; i += 512) {
            int n = i >> 4, dq = (i & 15) * 4;
            u32 v0 = 0, v1 = 0;
            if (t0 + n < KVS_NPB) {
                uint2 vv = *(const uint2*)(V16 + (size_t)(n0 + t0 + n) * 256 + h * 64 + dq);
                v0 = vv.x; v1 = vv.y;
            }
            #pragma unroll
            for (int j = 0; j < 4; ++j) {
                u16 val = (u16)(((j < 2) ? v0 : v1) >> ((j & 1) * 16));
                int d = dq + j;
                *(u16*)(VT + d * 128 + ((n * 2) ^ ((d & 7) << 4))) = val;
            }
        }
        __syncthreads();
        // ---- build kgT = bf16(kp * eg); accumulate ksum from the rounded values ----
        #pragma unroll
        for (int it = 0; it < 5; ++it) {
            int idx = tid + it * 512;          // 2560 = 320 rows x 8 n-chunks
            int row = idx >> 3, nc = idx & 7;
            u32 w_[4] = {0u, 0u, 0u, 0u};
            if (row < 300) {
                int k = row / MF, m = row - (row / MF) * MF;
                float s = 0.f;
                #pragma unroll
                for (int p = 0; p < 4; ++p) {
                    int na = nc * 8 + 2 * p, nb = na + 1;
                    u16 ha = f2bf(kpT[na][m] * egT[na][k]);
                    u16 hb = f2bf(kpT[nb][m] * egT[nb][k]);
                    w_[p] = (u32)ha | ((u32)hb << 16);
                    s += u2f(ha) + u2f(hb);
                }
                ksacc[it] += s;
            }
            *(uint4*)(kgT + row * 128 + ((nc * 16) ^ ((row & 7) << 4))) = make_uint4(w_[0], w_[1], w_[2], w_[3]);
        }
        __syncthreads();
        // ---- MFMA: wave owns C-tiles ct = wave*10 + i; kt = ct/4 (km), dt = ct%4 (d) ----
        #pragma unroll
        for (int kk = 0; kk < 2; ++kk) {
            const int kb = (kk * 32 + ((lane >> 4) * 8)) * 2;
            #pragma unroll
            for (int i = 0; i < 10; ++i) {
                int ct = wave * 10 + i;
                int kt = ct >> 2, dt = ct & 3;
                int ar = kt * 16 + (lane & 15);
                bf16x8 a = *(const bf16x8*)(kgT + ar * 128 + (kb ^ ((ar & 7) << 4)));
                int br = dt * 16 + (lane & 15);
                bf16x8 b = *(const bf16x8*)(VT + br * 128 + (kb ^ ((br & 7) << 4)));
                acc[i] = __builtin_amdgcn_mfma_f32_16x16x32_bf16(a, b, acc[i], 0, 0, 0);
            }
        }
    }
    // ---- write Pkvs partials: [chunk][h][300][64] ----
    #pragma unroll
    for (int i = 0; i < 10; ++i) {
        int ct = wave * 10 + i;
        int kt = ct >> 2, dt = ct & 3;
        int col = dt * 16 + (lane & 15);
        #pragma unroll
        for (int r = 0; r < 4; ++r) {
            int row = kt * 16 + ((lane >> 4) * 4) + r;
            if (row < 300)
                Pkvs[(((size_t)chunk * NH + h) * 300 + row) * 64 + col] = acc[i][r];
        }
    }
    // ---- ksum partial: reduce across the 8 n-chunk threads of each row ----
    #pragma unroll
    for (int it = 0; it < 5; ++it) {
        float v = ksacc[it];
        v += __shfl_xor(v, 1);
        v += __shfl_xor(v, 2);
        v += __shfl_xor(v, 4);
        int row = (tid + it * 512) >> 3;
        if ((tid & 7) == 0 && row < 300)
            Pksum[chunk * 1200 + h * 300 + row] = v;
    }
}

// ---------------- reduce partials -> kvs, ksum ----------------
__global__ __launch_bounds__(256) void k_reduce(const float* __restrict__ Pkvs, const float* __restrict__ Pksum,
                                                float* __restrict__ kvs, float* __restrict__ ksum)
{
    int i = blockIdx.x * 256 + threadIdx.x;
    if (i < NH * KG * MF * DH) {
        // kvs[i], i = (h*300 + km)*64 + d  ==  Pkvs inner layout
        float s = 0.f;
        for (int c = 0; c < KVS_CHUNKS; ++c) s += Pkvs[(size_t)c * (NH * 300 * 64) + i];
        kvs[i] = s;
    } else if (i < NH * KG * MF * DH + NH * KG * MF) {
        int j = i - NH * KG * MF * DH;
        float s = 0.f;
        for (int c = 0; c < KVS_CHUNKS; ++c) s += Pksum[c * 1200 + j];
        ksum[j] = s;
    }
}

// ---------------- per-edge attention weights -> link loss partials ----------------
__global__ __launch_bounds__(256) void k_edge(const int* __restrict__ ei,
                                              const u16* __restrict__ qp16, const u16* __restrict__ kp16,
                                              const float* __restrict__ an,
                                              const int* __restrict__ din, float* __restrict__ lossp)
{
    __shared__ float ls[64];
    int tid = threadIdx.x;
    int eg = tid >> 2, h = tid & 3;
    int e = blockIdx.x * 64 + eg;           // grid = NE/64 exact
    int s = ei[e], t = ei[NE + e];
    const uint4* qv = (const uint4*)(qp16 + ((size_t)t * NH + h) * 32);
    const uint4* kv = (const uint4*)(kp16 + ((size_t)s * NH + h) * 32);
    float num = 0.f;
    #pragma unroll
    for (int c = 0; c < 4; ++c) {
        uint4 a = qv[c], b = kv[c];
        num += u2f((u16)(a.x & 0xFFFF)) * u2f((u16)(b.x & 0xFFFF))
             + u2f((u16)(a.x >> 16))    * u2f((u16)(b.x >> 16))
             + u2f((u16)(a.y & 0xFFFF)) * u2f((u16)(b.y & 0xFFFF))
             + u2f((u16)(a.y >> 16))    * u2f((u16)(b.y >> 16))
             + u2f((u16)(a.z & 0xFFFF)) * u2f((u16)(b.z & 0xFFFF))
             + u2f((u16)(a.z >> 16))    * u2f((u16)(b.z >> 16))
             + u2f((u16)(a.w & 0xFFFF)) * u2f((u16)(b.w & 0xFFFF))
             + u2f((u16)(a.w >> 16))    * u2f((u16)(b.w >> 16));
    }
    float term = logf(num / an[(size_t)t * NH + h]);
    term += __shfl_xor(term, 1);
    term += __shfl_xor(term, 2);
    if (h == 0) ls[eg] = term / (float)din[t];
    __syncthreads();
    if (tid < 64) {
        float v = ls[tid];
        #pragma unroll
        for (int o = 32; o > 0; o >>= 1) v += __shfl_xor(v, o);
        if (tid == 0) atomicAdd(&lossp[blockIdx.x & 1023], v);
    }
}

// ---------------- attention readout: 48 nodes/block (3x16 sub-tiles) ----------------
#define AT_NT 48
__global__ __launch_bounds__(256) void k_attn(
    const float* __restrict__ qp, const float* __restrict__ kvs, const float* __restrict__ ksum,
    u16* __restrict__ zatt)
{
    __shared__ float qpTf[3][NH * 484];       // per 16-node sub-tile: plane h [m][j] stride 16
    __shared__ u32   kvbuf[NH * 964];         // bf16 kvs plane (stride 1928 u16); prologue alias: ksL fp32
    __shared__ float rdenL[3][16 * NH * KG];  // [sub][j][h][k]
    u16*   kvL16 = (u16*)kvbuf;
    float* ksL   = (float*)kvbuf;             // 1200 floats, dead before first kv stage
    int tid = threadIdx.x;
    int n0 = blockIdx.x * AT_NT;              // grid = NN/48 = 625 exact

    for (int i = tid; i < AT_NT * NH * MF; i += 256) {   // qp -> transposed LDS
        int j48 = i / (NH * MF); int r = i - j48 * (NH * MF);
        int h = r / MF; int m = r - h * MF;
        qpTf[j48 >> 4][h * 484 + m * 16 + (j48 & 15)] = qp[(size_t)(n0 + j48) * (NH * MF) + r];
    }
    for (int i = tid; i < NH * KG * MF; i += 256) ksL[i] = ksum[i];
    __syncthreads();
    for (int i = tid; i < AT_NT * NH * KG; i += 256) {   // rden = 1/(qp.ksum)
        int j48 = i / (NH * KG); int r = i - j48 * (NH * KG);
        int h = r / KG;
        int sub = j48 >> 4, j = j48 & 15;
        float s = 0.f;
        #pragma unroll
        for (int m = 0; m < MF; ++m) s += qpTf[sub][h * 484 + m * 16 + j] * ksL[r * MF + m];
        rdenL[sub][j * (NH * KG) + r] = 1.0f / s;
    }

    const int h  = tid >> 6;
    const int jg = (tid >> 4) & 3;
    const int dg = tid & 15;
    float acc[3][4][4] = {};
    for (int k = 0; k < KG; ++k) {
        __syncthreads();   // also protects ksL->kvL16 overlay on first iteration
        for (int i = tid; i < NH * MF * DH; i += 256) {  // stage kvs[:,k,:,:] as bf16
            int hh = i / (MF * DH); int r = i - hh * (MF * DH);
            kvL16[hh * 1928 + r] = f2bf(kvs[((size_t)(hh * KG + k) * MF) * DH + r]);
        }
        __syncthreads();
        float ps[3][4][4] = {};
        const u16* kb = kvL16 + h * 1928 + dg * 4;
        const float* qb0 = qpTf[0] + h * 484 + jg * 4;
        const float* qb1 = qpTf[1] + h * 484 + jg * 4;
        const float* qb2 = qpTf[2] + h * 484 + jg * 4;
        #pragma unroll
        for (int m = 0; m < MF; ++m) {
            ushort4 bu = *(const ushort4*)(kb + m * 64);
            float4 b = make_float4(u2f(bu.x), u2f(bu.y), u2f(bu.z), u2f(bu.w));
            float4 a0 = *(const float4*)(qb0 + m * 16);
            float4 a1 = *(const float4*)(qb1 + m * 16);
            float4 a2 = *(const float4*)(qb2 + m * 16);
            ps[0][0][0] += a0.x * b.x; ps[0][0][1] += a0.x * b.y; ps[0][0][2] += a0.x * b.z; ps[0][0][3] += a0.x * b.w;
            ps[0][1][0] += a0.y * b.x; ps[0][1][1] += a0.y * b.y; ps[0][1][2] += a0.y * b.z; ps[0][1][3] += a0.y * b.w;
            ps[0][2][0] += a0.z * b.x; ps[0][2][1] += a0.z * b.y; ps[0][2][2] += a0.z * b.z; ps[0][2][3] += a0.z * b.w;
            ps[0][3][0] += a0.w * b.x; ps[0][3][1] += a0.w * b.y; ps[0][3][2] += a0.w * b.z; ps[0][3][3] += a0.w * b.w;
            ps[1][0][0] += a1.x * b.x; ps[1][0][1] += a1.x * b.y; ps[1][0][2] += a1.x * b.z; ps[1][0][3] += a1.x * b.w;
            ps[1][1][0] += a1.y * b.x; ps[1][1][1] += a1.y * b.y; ps[1][1][2] += a1.y * b.z; ps[1][1][3] += a1.y * b.w;
            ps[1][2][0] += a1.z * b.x; ps[1][2][1] += a1.z * b.y; ps[1][2][2] += a1.z * b.z; ps[1][2][3] += a1.z * b.w;
            ps[1][3][0] += a1.w * b.x; ps[1][3][1] += a1.w * b.y; ps[1][3][2] += a1.w * b.z; ps[1][3][3] += a1.w * b.w;
            ps[2][0][0] += a2.x * b.x; ps[2][0][1] += a2.x * b.y; ps[2][0][2] += a2.x * b.z; ps[2][0][3] += a2.x * b.w;
            ps[2][1][0] += a2.y * b.x; ps[2][1][1] += a2.y * b.y; ps[2][1][2] += a2.y * b.z; ps[2][1][3] += a2.y * b.w;
            ps[2][2][0] += a2.z * b.x; ps[2][2][1] += a2.z * b.y; ps[2][2][2] += a2.z * b.z; ps[2][2][3] += a2.z * b.w;
            ps[2][3][0] += a2.w * b.x; ps[2][3][1] += a2.w * b.y; ps[2][3][2] += a2.w * b.z; ps[2][3][3] += a2.w * b.w;
        }
        #pragma unroll
        for (int sub = 0; sub < 3; ++sub)
            #pragma unroll
            for (int j4 = 0; j4 < 4; ++j4) {
                float rd = rdenL[sub][(jg * 4 + j4) * (NH * KG) + h * KG + k];
                #pragma unroll
                for (int d4 = 0; d4 < 4; ++d4) acc[sub][j4][d4] += ps[sub][j4][d4] * rd;
            }
    }
    #pragma unroll
    for (int sub = 0; sub < 3; ++sub)
        #pragma unroll
        for (int j4 = 0; j4 < 4; ++j4) {
            int n = n0 + sub * 16 + jg * 4 + j4;
            #pragma unroll
            for (int d4 = 0; d4 < 4; ++d4)
                zatt[(size_t)n * 256 + h * 64 + dg * 4 + d4] = f2bf(acc[sub][j4][d4] * (1.0f / KG));
        }
}

// ---------------- conv gather: wave-per-node, zero barriers ----------------
__global__ __launch_bounds__(256) void k_gather(
    const u16* __restrict__ zatt, const u16* __restrict__ V16,
    const int* __restrict__ csr, const float* __restrict__ wedge,
    const int* __restrict__ offn, const int* __restrict__ din,
    const float* __restrict__ params, u16* __restrict__ pre)
{
    int tid = threadIdx.x;
    int w = tid >> 6, l = tid & 63;
    int n = blockIdx.x * 4 + w;             // grid = NN/4 = 7500 exact
    float sigb = 1.f / (1.f + expf(-params[P_BBF + (l >> 4)]));   // head of elems l*4..l*4+3
    int dn = din[n], o0 = offn[n];
    float c0 = 0.f, c1 = 0.f, c2 = 0.f, c3 = 0.f;
    for (int t0 = 0; t0 < dn; t0 += 64) {
        int cnt = min(64, dn - t0);
        int myIdx = 0; float myW = 0.f;
        if (l < cnt) { myIdx = csr[o0 + t0 + l]; myW = wedge[o0 + t0 + l]; }
        int j = 0;
        for (; j + 7 < cnt; j += 8) {       // 8 rows in flight (wave-uniform trip count)
            int   s0 = __shfl(myIdx, j),     s1 = __shfl(myIdx, j + 1);
            int   s2 = __shfl(myIdx, j + 2), s3 = __shfl(myIdx, j + 3);
            int   s4 = __shfl(myIdx, j + 4), s5 = __shfl(myIdx, j + 5);
            int   s6 = __shfl(myIdx, j + 6), s7 = __shfl(myIdx, j + 7);
            float w0 = __shfl(myW, j),     w1 = __shfl(myW, j + 1);
            float w2 = __shfl(myW, j + 2), w3 = __shfl(myW, j + 3);
            float w4 = __shfl(myW, j + 4), w5 = __shfl(myW, j + 5);
            float w6 = __shfl(myW, j + 6), w7 = __shfl(myW, j + 7);
            uint2 a0 = *(const uint2*)(V16 + (size_t)s0 * 256 + l * 4);
            uint2 a1 = *(const uint2*)(V16 + (size_t)s1 * 256 + l * 4);
            uint2 a2 = *(const uint2*)(V16 + (size_t)s2 * 256 + l * 4);
            uint2 a3 = *(const uint2*)(V16 + (size_t)s3 * 256 + l * 4);
            uint2 a4 = *(const uint2*)(V16 + (size_t)s4 * 256 + l * 4);
            uint2 a5 = *(const uint2*)(V16 + (size_t)s5 * 256 + l * 4);
            uint2 a6 = *(const uint2*)(V16 + (size_t)s6 * 256 + l * 4);
            uint2 a7 = *(const uint2*)(V16 + (size_t)s7 * 256 + l * 4);
            c0 += w0 * u2f((u16)(a0.x & 0xFFFF)) + w1 * u2f((u16)(a1.x & 0xFFFF))
                + w2 * u2f((u16)(a2.x & 0xFFFF)) + w3 * u2f((u16)(a3.x & 0xFFFF))
                + w4 * u2f((u16)(a4.x & 0xFFFF)) + w5 * u2f((u16)(a5.x & 0xFFFF))
                + w6 * u2f((u16)(a6.x & 0xFFFF)) + w7 * u2f((u16)(a7.x & 0xFFFF));
            c1 += w0 * u2f((u16)(a0.x >> 16)) + w1 * u2f((u16)(a1.x >> 16))
                + w2 * u2f((u16)(a2.x >> 16)) + w3 * u2f((u16)(a3.x >> 16))
                + w4 * u2f((u16)(a4.x >> 16)) + w5 * u2f((u16)(a5.x >> 16))
                + w6 * u2f((u16)(a6.x >> 16)) + w7 * u2f((u16)(a7.x >> 16));
            c2 += w0 * u2f((u16)(a0.y & 0xFFFF)) + w1 * u2f((u16)(a1.y & 0xFFFF))
                + w2 * u2f((u16)(a2.y & 0xFFFF)) + w3 * u2f((u16)(a3.y & 0xFFFF))
                + w4 * u2f((u16)(a4.y & 0xFFFF)) + w5 * u2f((u16)(a5.y & 0xFFFF))
                + w6 * u2f((u16)(a6.y & 0xFFFF)) + w7 * u2f((u16)(a7.y & 0xFFFF));
            c3 += w0 * u2f((u16)(a0.y >> 16)) + w1 * u2f((u16)(a1.y >> 16))
                + w2 * u2f((u16)(a2.y >> 16)) + w3 * u2f((u16)(a3.y >> 16))
                + w4 * u2f((u16)(a4.y >> 16)) + w5 * u2f((u16)(a5.y >> 16))
                + w6 * u2f((u16)(a6.y >> 16)) + w7 * u2f((u16)(a7.y >> 16));
        }
        for (; j < cnt; ++j) {
            int   s0 = __shfl(myIdx, j);
            float w0 = __shfl(myW, j);
            uint2 a0 = *(const uint2*)(V16 + (size_t)s0 * 256 + l * 4);
            c0 += w0 * u2f((u16)(a0.x & 0xFFFF));
            c1 += w0 * u2f((u16)(a0.x >> 16));
            c2 += w0 * u2f((u16)(a0.y & 0xFFFF));
            c3 += w0 * u2f((u16)(a0.y >> 16));
        }
    }
    uint2 za = *(const uint2*)(zatt + (size_t)n * 256 + l * 4);
    float e0 = u2f((u16)(za.x & 0xFFFF)) + sigb * c0;
    float e1 = u2f((u16)(za.x >> 16))    + sigb * c1;
    float e2 = u2f((u16)(za.y & 0xFFFF)) + sigb * c2;
    float e3 = u2f((u16)(za.y >> 16))    + sigb * c3;
    uint2 r;
    r.x = (u32)f2bf(e0) | ((u32)f2bf(e1) << 16);
    r.y = (u32)f2bf(e2) | ((u32)f2bf(e3) << 16);
    *(uint2*)(pre + (size_t)n * 256 + l * 4) = r;
}

// ---------------- out = pre(bf16) x Wo^T via MFMA (Wo hi/lo split on the fly) ----------------
// 64-row tiles, grid 469. Wo (64KB fp32) read 469x instead of 30000x.
__global__ __launch_bounds__(256) void k_out(
    const u16* __restrict__ pre, const float* __restrict__ params, float* __restrict__ out)
{
    __shared__ __align__(16) char smemc[24576];   // As(8KB) | BsH(8KB) | BsL(8KB)
    char* As  = smemc;
    char* BsH = smemc + 8192;
    char* BsL = smemc + 16384;
    const int tid = threadIdx.x;
    const int bm = blockIdx.x * 64;
    const int wave = tid >> 6, lane = tid & 63;
    const int wm = wave >> 1, wn = wave & 1;
    const int sr = tid >> 2;
    const int sc = (tid & 3) * 16;

    f32x4 acc[2][2] = {};

    for (int k0 = 0; k0 < 256; k0 += 64) {
        __syncthreads();
        int byt0 = sr * 128 + (((sc + 0) * 2) ^ ((sr & 7) << 4));
        int byt1 = sr * 128 + (((sc + 8) * 2) ^ ((sr & 7) << 4));
        {   // ---- stage A: pre rows (bf16 copy) ----
            int row = bm + sr;
            uint4 v0 = make_uint4(0, 0, 0, 0), v1 = v0;
            if (row < NN) {
                const uint4* p = (const uint4*)(pre + (size_t)row * 256 + k0 + sc);
                v0 = p[0]; v1 = p[1];
            }
            *(uint4*)(As + byt0) = v0;
            *(uint4*)(As + byt1) = v1;
        }
        {   // ---- stage B: Wo fp32 -> hi/lo bf16 planes ----
            float x[16];
            const float4* wr = (const float4*)(params + P_WOF + (size_t)sr * 256 + k0 + sc);
            #pragma unroll
            for (int q4 = 0; q4 < 4; ++q4) {
                float4 v = wr[q4];
                x[q4 * 4 + 0] = v.x; x[q4 * 4 + 1] = v.y;
                x[q4 * 4 + 2] = v.z; x[q4 * 4 + 3] = v.w;
            }
            #pragma unroll
            for (int j8 = 0; j8 < 2; ++j8) {
                u32 hw[4], lw[4];
                #pragma unroll
                for (int p = 0; p < 4; ++p) {
                    float a = x[j8 * 8 + 2 * p], b2 = x[j8 * 8 + 2 * p + 1];
                    u16 ha = f2bf(a), hb = f2bf(b2);
                    hw[p] = (u32)ha | ((u32)hb << 16);
                    u16 la = f2bf(a - u2f(ha)), lb = f2bf(b2 - u2f(hb));
                    lw[p] = (u32)la | ((u32)lb << 16);
                }
                int byt = sr * 128 + (((sc + j8 * 8) * 2) ^ ((sr & 7) << 4));
                *(uint4*)(BsH + byt) = make_uint4(hw[0], hw[1], hw[2], hw[3]);
                *(uint4*)(BsL + byt) = make_uint4(lw[0], lw[1], lw[2], lw[3]);
            }
        }
        __syncthreads();
        #pragma unroll
        for (int kk = 0; kk < 2; ++kk) {
            const int kb = (kk * 32 + ((lane >> 4) * 8)) * 2;
            bf16x8 a[2], bh[2], bl[2];
            #pragma unroll
            for (int i = 0; i < 2; ++i) {
                int ar = 32 * wm + 16 * i + (lane & 15);
                int ab = ar * 128 + (kb ^ ((ar & 7) << 4));
                a[i] = *(const bf16x8*)(As + ab);
                int br = 32 * wn + 16 * i + (lane & 15);
                int bb2 = br * 128 + (kb ^ ((br & 7) << 4));
                bh[i] = *(const bf16x8*)(BsH + bb2);
                bl[i] = *(const bf16x8*)(BsL + bb2);
            }
            #pragma unroll
            for (int i = 0; i < 2; ++i)
                #pragma unroll
                for (int nf = 0; nf < 2; ++nf) {
                    acc[i][nf] = __builtin_amdgcn_mfma_f32_16x16x32_bf16(a[i], bh[nf], acc[i][nf], 0, 0, 0);
                    acc[i][nf] = __builtin_amdgcn_mfma_f32_16x16x32_bf16(a[i], bl[nf], acc[i][nf], 0, 0, 0);
                }
        }
    }
    #pragma unroll
    for (int i = 0; i < 2; ++i)
        #pragma unroll
        for (int nf = 0; nf < 2; ++nf) {
            int col = 32 * wn + 16 * nf + (lane & 15);
            float bias = params[P_WOBF + col];
            #pragma unroll
            for (int r2 = 0; r2 < 4; ++r2) {
                int row = bm + 32 * wm + 16 * i + ((lane >> 4) * 4) + r2;
                if (row < NN) out[(size_t)row * 64 + col] = acc[i][nf][r2] + bias;
            }
        }
}

// ---------------- loss finalize ----------------
__global__ __launch_bounds__(256) void k_loss(const float* __restrict__ lossp, float* __restrict__ out) {
    __shared__ float s[256];
    int tid = threadIdx.x;
    float v = 0.f;
    for (int i = tid; i < 1024; i += 256) v += lossp[i];
    s[tid] = v;
    __syncthreads();
    for (int o = 128; o > 0; o >>= 1) {
        if (tid < o) s[tid] += s[tid + o];
        __syncthreads();
    }
    if (tid == 0) out[(size_t)NN * 64] = s[0] / (float)(NE * NH);   // fp32 output
}

extern "C" void kernel_launch(void* const* d_in, const int* in_sizes, int n_in,
                              void* d_out, int out_size, void* d_ws, size_t ws_size,
                              hipStream_t stream)
{
    const void* z    = d_in[0];
    const int*  ei   = (const int*)d_in[1];
    const void* taup = d_in[2];
    const void* gum  = d_in[3];
    const void* proj = d_in[4];
    const void* Wq   = d_in[5];
    const void* bq   = d_in[6];
    const void* Wk   = d_in[7];
    const void* bk   = d_in[8];
    const void* Wv   = d_in[9];
    const void* bv   = d_in[10];
    const void* Wo   = d_in[11];
    const void* Wob  = d_in[12];
    const void* bb   = d_in[13];
    float* out = (float*)d_out;

    // ---- workspace carve-up (fp32 units), total ~67 MB ----
    u16*   V16    = (u16*)d_ws;                    //  7,680,000 u16 : [N,256] bf16 V
    float* qpb    = (float*)d_ws + 3840000;        //  3,600,000 : [N,H,M]
    float* kpb    = qpb + (size_t)NN * NH * MF;    //  3,600,000 : dashK then kp in-place
    float* diagK  = kpb + (size_t)NN * NH * MF;    //    120,000
    float* anb    = diagK + (size_t)NN * NH;       //    120,000
    u16*   zatt   = (u16*)kpb;                     //  reuses kpb+diagK+anb (dead after k_edge)
    int*   csr    = (int*)(anb + (size_t)NN * NH); //    480,000
    int*   offn   = csr + NE;                      //     30,000
    float* params = (float*)(offn + NN);           //    215,749 (+pad to 215,752)
    // ---- zeroed accumulator region ----
    float* kvs    = params + 215752;               //     76,800 : [H,K,M,D]
    float* ksum   = kvs + NH * KG * MF * DH;       //      1,200 : [H,K,M]
    float* kpsum  = ksum + NH * KG * MF;           //        120 : [H,M]
    int*   din    = (int*)(kpsum + NH * MF);       //     30,000
    int*   doutd  = din + NN;                      //     30,000
    int*   fill   = doutd + NN;                    //     30,000
    int*   counter = fill + NN;                    //          4
    u32*   stab   = (u32*)(counter + 4);           //          4
    float* lossp  = (float*)(stab + 4);            //      1,024
    int*   flag   = (int*)(lossp + 1024);          //          4
    float* wedge  = (float*)(flag + 4);            //    480,000 (not zeroed; fully written)
    u16*   qp16   = (u16*)(wedge + NE);            //  3,840,000 u16 : [N,H,32] bf16 qp
    u16*   kp16   = qp16 + (size_t)NN * NH * 32;   //  3,840,000 u16 : [N,H,32] bf16 kp
    // kvs partials overlay qp16+kp16 (15.36 MB, exact fit: 50*4*300*64 floats);
    // alive only between k_kvs and k_reduce, after qp16/kp16's last reader (k_edge).
    float* Pkvs   = (float*)qp16;
    float* Pksum  = (float*)(kp16 + (size_t)NN * NH * 32);   //  60,000 floats (new tail)
    // W hi/lo bf16 planes overlay kp16 (dead until k_kp writes it, after k_gemm_feat)
    u16*   Whb    = kp16;                          //    196,608 u16 : [768][256] W hi
    u16*   Wlb    = kp16 + 196608;                 //    196,608 u16 : [768][256] W lo
    // pre[N,256] bf16 overlays qp16+kp16 (7,680,000 u16 exactly); alive only
    // between k_gather and k_out, after Pkvs's last reader (k_reduce).
    u16*   pre    = qp16;
    size_t zero_bytes = (size_t)((char*)(flag + 4) - (char*)kvs);

    hipMemsetAsync(kvs, 0, zero_bytes, stream);

    k_detect<<<dim3(1), dim3(64), 0, stream>>>((const u16*)z, flag);
    k_cvt_params<<<dim3((P_TOTAL + 255) / 256), dim3(256), 0, stream>>>(
        Wq, Wk, Wv, bq, bk, bv, Wo, Wob, bb, proj, taup, params, flag);
    k_cvt_w<<<dim3(768), dim3(256), 0, stream>>>(params, Whb, Wlb);

    k_deg <<<dim3((NE + 255) / 256), dim3(256), 0, stream>>>(ei, din, doutd);
    k_off <<<dim3((NN + 255) / 256), dim3(256), 0, stream>>>(din, offn, counter);
    k_fill<<<dim3((NE + 255) / 256), dim3(256), 0, stream>>>(ei, offn, fill, csr, din, doutd, wedge);
    k_gemm_feat<<<dim3((NN + 63) / 64, 12), dim3(256), 0, stream>>>(
        z, params, flag, Whb, Wlb, V16, qpb, qp16, kpb, diagK, stab);
    k_kp  <<<dim3(NN * NH / 64), dim3(256), 0, stream>>>(kpb, diagK, stab, kpsum, kp16);
    k_an  <<<dim3((NN * NH + 255) / 256), dim3(256), 0, stream>>>(qpb, kpsum, anb);
    k_edge<<<dim3(NE / 64), dim3(256), 0, stream>>>(ei, qp16, kp16, anb, din, lossp);
    // qp16/kp16 dead from here; Pkvs overlays them (stream-ordered)
    k_kvs <<<dim3(KVS_CHUNKS, NH), dim3(512), 0, stream>>>(kpb, gum, V16, flag, Pkvs, Pksum);
    k_reduce<<<dim3((NH * KG * MF * DH + NH * KG * MF + 255) / 256), dim3(256), 0, stream>>>(
        Pkvs, Pksum, kvs, ksum);
    // zatt overwrites kpb/diagK/anb from here on (stream-ordered after their last readers)
    k_attn<<<dim3(NN / AT_NT), dim3(256), 0, stream>>>(qpb, kvs, ksum, zatt);
    // pre overlays qp16/kp16 (Pkvs dead after k_reduce)
    k_gather<<<dim3(NN / 4), dim3(256), 0, stream>>>(zatt, V16, csr, wedge, offn, din, params, pre);
    k_out<<<dim3((NN + 63) / 64), dim3(256), 0, stream>>>(pre, params, out);
    k_loss<<<dim3(1), dim3(256), 0, stream>>>(lossp, out);
}